// Round 7
// baseline (249.651 us; speedup 1.0000x reference)
//
#include <hip/hip_runtime.h>

typedef __bf16 bf16_t;
typedef bf16_t bf16x8 __attribute__((ext_vector_type(8)));
typedef bf16_t bf16x4 __attribute__((ext_vector_type(4)));
typedef float  f32x4  __attribute__((ext_vector_type(4)));
typedef float  f32x16 __attribute__((ext_vector_type(16)));
typedef unsigned int u32;
typedef u32 u32x2 __attribute__((ext_vector_type(2)));
typedef u32 u32x4 __attribute__((ext_vector_type(4)));

#define T_SEQ 2048
#define C_DIM 1024
#define NH    16
#define DH    64
#define BATCH 4
#define M_TOK (BATCH * T_SEQ)   // 8192

// Q pre-scale: 1/sqrt(64) * log2(e)  -> softmax computed in exp2 domain
#define Q_SCALE 0.1803368801111137f
#define DEFER_THR 8.0f

#define AS1 __attribute__((address_space(1)))
#define AS3 __attribute__((address_space(3)))

__device__ __forceinline__ void gld_lds16(const bf16_t* g, bf16_t* l) {
  __builtin_amdgcn_global_load_lds(
      (const AS1 u32*)(uintptr_t)g,
      (AS3 u32*)(u32)(uintptr_t)l, 16, 0, 0);
}

// v_permlane32_swap_b32: swaps a[32+i] <-> b[i].
__device__ __forceinline__ void plswap(u32& a, u32& b) {
  u32x2 r = __builtin_amdgcn_permlane32_swap(a, b, false, false);
  a = r[0]; b = r[1];
}
__device__ __forceinline__ float xmax32(float x) {
  u32 a = __builtin_bit_cast(u32, x), b = a;
  plswap(a, b);
  return fmaxf(__builtin_bit_cast(float, a), __builtin_bit_cast(float, b));
}
__device__ __forceinline__ float xsum32(float x) {
  u32 a = __builtin_bit_cast(u32, x), b = a;
  plswap(a, b);
  return __builtin_bit_cast(float, a) + __builtin_bit_cast(float, b);
}

// ---------------------------------------------------------------------------
// prep: x f32 -> bf16
// ---------------------------------------------------------------------------
__global__ __launch_bounds__(256) void msa_cvt_x(const float* __restrict__ x,
                                                 bf16_t* __restrict__ xb, int n4) {
  int i = blockIdx.x * 256 + threadIdx.x;
  if (i < n4) {
    const float4 v = ((const float4*)x)[i];
    bf16x4 o;
    o[0] = (bf16_t)v.x; o[1] = (bf16_t)v.y; o[2] = (bf16_t)v.z; o[3] = (bf16_t)v.w;
    ((bf16x4*)xb)[i] = o;
  }
}

// ---------------------------------------------------------------------------
// prep: weight transpose+convert: w[k][n] f32 -> wt[n][k] bf16
// ---------------------------------------------------------------------------
__global__ __launch_bounds__(256) void msa_transpose_w(
    const float* __restrict__ wq, const float* __restrict__ wk,
    const float* __restrict__ wv, const float* __restrict__ wo,
    bf16_t* __restrict__ wt_qkv, bf16_t* __restrict__ wt_o) {
  __shared__ float tile[32][33];
  const int a = blockIdx.z;
  const float* src = (a == 0) ? wq : (a == 1) ? wk : (a == 2) ? wv : wo;
  bf16_t* dst = (a < 3) ? (wt_qkv + (size_t)a * C_DIM * C_DIM) : wt_o;
  const int tx = threadIdx.x & 31, ty = threadIdx.x >> 5;
  const int bi = blockIdx.y * 32, bj = blockIdx.x * 32;
#pragma unroll
  for (int p = 0; p < 4; p++) {
    int r = p * 8 + ty;
    tile[r][tx] = src[(size_t)(bi + r) * C_DIM + bj + tx];
  }
  __syncthreads();
#pragma unroll
  for (int p = 0; p < 4; p++) {
    int r = p * 8 + ty;
    dst[(size_t)(bj + r) * C_DIM + bi + tx] = (bf16_t)tile[tx][r];
  }
}

// ---------------------------------------------------------------------------
// QKV GEMM, m97 structure
// ---------------------------------------------------------------------------
__global__ __launch_bounds__(256) void msa_gemm_qkv(
    const bf16_t* __restrict__ xb, const bf16_t* __restrict__ wt,
    const float* __restrict__ bq, const float* __restrict__ bk,
    const float* __restrict__ bv,
    bf16_t* __restrict__ qo, bf16_t* __restrict__ ko, bf16_t* __restrict__ vto) {
  __shared__ bf16_t lA[128 * 32];
  __shared__ bf16_t lB[128 * 32];
  const int tid = threadIdx.x;
  const int w = tid >> 6, lane = tid & 63;
  const int lr = lane & 15, lg = lane >> 4;
  const int m0 = blockIdx.y * 128;
  const int n0 = blockIdx.x * 128;
  const int wm = (w >> 1) * 64, wn = (w & 1) * 64;

  const int srow = tid >> 2, scol = (tid & 3) * 8;
  const bf16_t* ga = xb + (size_t)(m0 + srow) * C_DIM + scol;
  const bf16_t* gb = wt + (size_t)(n0 + srow) * C_DIM + scol;

  f32x4 acc[4][4];
#pragma unroll
  for (int i = 0; i < 4; i++)
#pragma unroll
    for (int j = 0; j < 4; j++) acc[i][j] = (f32x4){0.f, 0.f, 0.f, 0.f};

  for (int k0 = 0; k0 < C_DIM; k0 += 32) {
    gld_lds16(ga + k0, &lA[tid * 8]);
    gld_lds16(ga + (size_t)64 * C_DIM + k0, &lA[2048 + tid * 8]);
    gld_lds16(gb + k0, &lB[tid * 8]);
    gld_lds16(gb + (size_t)64 * C_DIM + k0, &lB[2048 + tid * 8]);
    __syncthreads();
    bf16x8 a[4], b[4];
#pragma unroll
    for (int mb = 0; mb < 4; mb++)
      a[mb] = *(const bf16x8*)&lA[(wm + mb * 16 + lr) * 32 + lg * 8];
#pragma unroll
    for (int nb = 0; nb < 4; nb++)
      b[nb] = *(const bf16x8*)&lB[(wn + nb * 16 + lr) * 32 + lg * 8];
#pragma unroll
    for (int mb = 0; mb < 4; mb++)
#pragma unroll
      for (int nb = 0; nb < 4; nb++)
        acc[mb][nb] = __builtin_amdgcn_mfma_f32_16x16x32_bf16(a[mb], b[nb], acc[mb][nb], 0, 0, 0);
    __syncthreads();
  }

#pragma unroll
  for (int nb = 0; nb < 4; nb++) {
    const int n = n0 + wn + nb * 16 + lr;
    const int g = n >> 10, c = n & 1023, h = c >> 6, d = c & 63;
    const float bias = (g == 0) ? bq[c] : (g == 1) ? bk[c] : bv[c];
#pragma unroll
    for (int mb = 0; mb < 4; mb++) {
#pragma unroll
      for (int r = 0; r < 4; r++) {
        const int m = m0 + wm + mb * 16 + lg * 4 + r;
        const int bi = m >> 11, t = m & (T_SEQ - 1);
        float v = acc[mb][nb][r] + bias;
        if (g == 0)
          qo[(((size_t)bi * NH + h) * T_SEQ + t) * DH + d] = (bf16_t)(v * Q_SCALE);
        else if (g == 1)
          ko[(((size_t)bi * NH + h) * T_SEQ + t) * DH + d] = (bf16_t)v;
        else
          vto[(((size_t)bi * NH + h) * DH + d) * T_SEQ + t] = (bf16_t)v;
      }
    }
  }
}

// ---------------------------------------------------------------------------
// attn softmax + pack (permlane32_swap: no LDS, no selects)
// ---------------------------------------------------------------------------
__device__ __forceinline__ void sm_pack(f32x16& s, float& m_run, float& l_run,
                                        f32x16& o0, f32x16& o1,
                                        bf16x8& pa0, bf16x8& pa1) {
  float t0 = fmaxf(fmaxf(s[0], s[1]), s[2]);
  float t1 = fmaxf(fmaxf(s[3], s[4]), s[5]);
  float t2 = fmaxf(fmaxf(s[6], s[7]), s[8]);
  float t3 = fmaxf(fmaxf(s[9], s[10]), s[11]);
  float t4 = fmaxf(fmaxf(s[12], s[13]), s[14]);
  float t5 = fmaxf(fmaxf(t0, t1), s[15]);
  float mt = fmaxf(fmaxf(fmaxf(t2, t3), t4), t5);
  mt = xmax32(mt);

  if (__any(mt > m_run + DEFER_THR)) {
    const float mnew = fmaxf(m_run, mt);
    const float al = __builtin_amdgcn_exp2f(m_run - mnew);
    m_run = mnew;
    l_run *= al;
#pragma unroll
    for (int r = 0; r < 16; r++) { o0[r] *= al; o1[r] *= al; }
  }

#pragma unroll
  for (int r = 0; r < 16; r++) s[r] = __builtin_amdgcn_exp2f(s[r] - m_run);
  {
    float a0 = (s[0] + s[1]) + (s[2] + s[3]);
    float a1 = (s[4] + s[5]) + (s[6] + s[7]);
    float a2 = (s[8] + s[9]) + (s[10] + s[11]);
    float a3 = (s[12] + s[13]) + (s[14] + s[15]);
    l_run += xsum32((a0 + a1) + (a2 + a3));
  }

  u32 pk8[8];
#pragma unroll
  for (int i = 0; i < 8; i++) {
    const unsigned short lo = __builtin_bit_cast(unsigned short, (bf16_t)s[2 * i]);
    const unsigned short hh = __builtin_bit_cast(unsigned short, (bf16_t)s[2 * i + 1]);
    pk8[i] = ((u32)hh << 16) | (u32)lo;
  }
  u32 f0w0 = pk8[0], f0w2 = pk8[2];
  u32 f0w1 = pk8[1], f0w3 = pk8[3];
  u32 f1w0 = pk8[4], f1w2 = pk8[6];
  u32 f1w1 = pk8[5], f1w3 = pk8[7];
  plswap(f0w0, f0w2);
  plswap(f0w1, f0w3);
  plswap(f1w0, f1w2);
  plswap(f1w1, f1w3);
  const u32x4 q0v = {f0w0, f0w1, f0w2, f0w3};
  const u32x4 q1v = {f1w0, f1w1, f1w2, f1w3};
  pa0 = __builtin_bit_cast(bf16x8, q0v);
  pa1 = __builtin_bit_cast(bf16x8, q1v);
}

__device__ __forceinline__ void store_o(f32x16& o0, f32x16& o1, float l_fin,
                                        bf16_t* __restrict__ orow, const int hi) {
  const float inv = 1.0f / l_fin;
#pragma unroll
  for (int db = 0; db < 2; db++) {
#pragma unroll
    for (int r = 0; r < 16; r += 2) {
      const int d = db * 32 + (r & 3) + 8 * (r >> 2) + 4 * hi;
      const float v0 = (db ? o1[r] : o0[r]) * inv;
      const float v1 = (db ? o1[r + 1] : o0[r + 1]) * inv;
      const unsigned short b0 = __builtin_bit_cast(unsigned short, (bf16_t)v0);
      const unsigned short b1 = __builtin_bit_cast(unsigned short, (bf16_t)v1);
      *reinterpret_cast<u32*>(orow + d) = ((u32)b1 << 16) | (u32)b0;
    }
  }
}

// ---------------------------------------------------------------------------
// Flash attention (causal): dual-stream pairs (R4 structure) with BOTH K and
// V ping-pong prefetched one full iteration ahead (~full-chain slack covers
// L3/HBM latency; V same-iteration load was the exposed ~800cy in R4/R6).
// Grid (bh=64, pair=32), 1 wave per block, no LDS, no merge.
// ---------------------------------------------------------------------------
__global__ __launch_bounds__(64, 2) void msa_attn32(
    const bf16_t* __restrict__ Q, const bf16_t* __restrict__ K,
    const bf16_t* __restrict__ Vt, bf16_t* __restrict__ O) {
  const int lane = threadIdx.x;
  const int l31 = lane & 31;
  const int hi = lane >> 5;
  const int bh = blockIdx.x;
  const int p = blockIdx.y;
  const int tS = p, tL = 63 - p;
  const int q0S = tS * 32, q0L = tL * 32;

  const bf16_t* Qh = Q + (size_t)bh * T_SEQ * DH;
  const bf16_t* Kh = K + (size_t)bh * T_SEQ * DH;
  const bf16_t* Vh = Vt + (size_t)bh * DH * T_SEQ;

  bf16x8 qfL[4], qfS[4];
#pragma unroll
  for (int dc = 0; dc < 4; dc++) {
    qfL[dc] = *(const bf16x8*)(Qh + (size_t)(q0L + l31) * DH + dc * 16 + hi * 8);
    qfS[dc] = *(const bf16x8*)(Qh + (size_t)(q0S + l31) * DH + dc * 16 + hi * 8);
  }

  f32x16 oL0, oL1, oS0, oS1;
#pragma unroll
  for (int r = 0; r < 16; r++) { oL0[r] = 0.f; oL1[r] = 0.f; oS0[r] = 0.f; oS1[r] = 0.f; }
  float mL = -1e30f, lL = 0.f, mS = -1e30f, lS = 0.f;
  const f32x16 z16 = {};

  // preload tile 0: K and V
  bf16x8 kA[4], kB[4], vA[4], vB[4];
#pragma unroll
  for (int dc = 0; dc < 4; dc++)
    kA[dc] = *(const bf16x8*)(Kh + (size_t)l31 * DH + dc * 16 + hi * 8);
  vA[0] = *(const bf16x8*)(Vh + (size_t)l31 * T_SEQ + hi * 8);
  vA[1] = *(const bf16x8*)(Vh + (size_t)l31 * T_SEQ + 16 + hi * 8);
  vA[2] = *(const bf16x8*)(Vh + (size_t)(32 + l31) * T_SEQ + hi * 8);
  vA[3] = *(const bf16x8*)(Vh + (size_t)(32 + l31) * T_SEQ + 16 + hi * 8);

  int kt = 0;

  // body: compute with (KC,VC) for tile kt; prefetch tile kt+1 into (KN,VN)
#define ATTN_BODY(KC, VC, KN, VN)                                                  \
  {                                                                                \
    const int jn = (kt < tL) ? (kt + 1) * 32 : 0;                                  \
    _Pragma("unroll") for (int dc = 0; dc < 4; dc++)                               \
        KN[dc] = *(const bf16x8*)(Kh + (size_t)(jn + l31) * DH + dc * 16 + hi * 8);\
    VN[0] = *(const bf16x8*)(Vh + (size_t)l31 * T_SEQ + jn + hi * 8);              \
    VN[1] = *(const bf16x8*)(Vh + (size_t)l31 * T_SEQ + jn + 16 + hi * 8);         \
    VN[2] = *(const bf16x8*)(Vh + (size_t)(32 + l31) * T_SEQ + jn + hi * 8);       \
    VN[3] = *(const bf16x8*)(Vh + (size_t)(32 + l31) * T_SEQ + jn + 16 + hi * 8);  \
    const bool actS = (kt <= tS);                                                  \
    f32x16 sL = __builtin_amdgcn_mfma_f32_32x32x16_bf16(KC[0], qfL[0], z16, 0, 0, 0); \
    _Pragma("unroll") for (int dc = 1; dc < 4; dc++)                               \
        sL = __builtin_amdgcn_mfma_f32_32x32x16_bf16(KC[dc], qfL[dc], sL, 0, 0, 0);\
    f32x16 sS;                                                                     \
    if (actS) {                                                                    \
      sS = __builtin_amdgcn_mfma_f32_32x32x16_bf16(KC[0], qfS[0], z16, 0, 0, 0);   \
      _Pragma("unroll") for (int dc = 1; dc < 4; dc++)                             \
          sS = __builtin_amdgcn_mfma_f32_32x32x16_bf16(KC[dc], qfS[dc], sS, 0, 0, 0); \
    }                                                                              \
    if (kt == tL) {                                                                \
      _Pragma("unroll") for (int r = 0; r < 16; r++) {                             \
        const int jrow = (r & 3) + 8 * (r >> 2) + 4 * hi;                          \
        if (jrow > l31) sL[r] = -1e30f;                                            \
      }                                                                            \
    }                                                                              \
    if (kt == tS) {                                                                \
      _Pragma("unroll") for (int r = 0; r < 16; r++) {                             \
        const int jrow = (r & 3) + 8 * (r >> 2) + 4 * hi;                          \
        if (jrow > l31) sS[r] = -1e30f;                                            \
      }                                                                            \
    }                                                                              \
    bf16x8 paL0, paL1;                                                             \
    sm_pack(sL, mL, lL, oL0, oL1, paL0, paL1);                                     \
    oL0 = __builtin_amdgcn_mfma_f32_32x32x16_bf16(VC[0], paL0, oL0, 0, 0, 0);      \
    oL1 = __builtin_amdgcn_mfma_f32_32x32x16_bf16(VC[2], paL0, oL1, 0, 0, 0);      \
    oL0 = __builtin_amdgcn_mfma_f32_32x32x16_bf16(VC[1], paL1, oL0, 0, 0, 0);      \
    oL1 = __builtin_amdgcn_mfma_f32_32x32x16_bf16(VC[3], paL1, oL1, 0, 0, 0);      \
    if (actS) {                                                                    \
      bf16x8 paS0, paS1;                                                           \
      sm_pack(sS, mS, lS, oS0, oS1, paS0, paS1);                                   \
      oS0 = __builtin_amdgcn_mfma_f32_32x32x16_bf16(VC[0], paS0, oS0, 0, 0, 0);    \
      oS1 = __builtin_amdgcn_mfma_f32_32x32x16_bf16(VC[2], paS0, oS1, 0, 0, 0);    \
      oS0 = __builtin_amdgcn_mfma_f32_32x32x16_bf16(VC[1], paS1, oS0, 0, 0, 0);    \
      oS1 = __builtin_amdgcn_mfma_f32_32x32x16_bf16(VC[3], paS1, oS1, 0, 0, 0);    \
    }                                                                              \
  }

  while (kt <= tL) {
    ATTN_BODY(kA, vA, kB, vB);
    kt++;
    if (kt > tL) break;
    ATTN_BODY(kB, vB, kA, vA);
    kt++;
  }
#undef ATTN_BODY

  const int b = bh >> 4, h = bh & 15;
  store_o(oL0, oL1, lL, O + ((size_t)b * T_SEQ + q0L + l31) * C_DIM + h * DH, hi);
  store_o(oS0, oS1, lS, O + ((size_t)b * T_SEQ + q0S + l31) * C_DIM + h * DH, hi);
}

// ---------------------------------------------------------------------------
// Output projection, m97 structure
// ---------------------------------------------------------------------------
__global__ __launch_bounds__(256) void msa_gemm_out(
    const bf16_t* __restrict__ ab, const bf16_t* __restrict__ wt,
    const float* __restrict__ bo, float* __restrict__ out) {
  __shared__ bf16_t lA[128 * 32];
  __shared__ bf16_t lB[128 * 32];
  const int tid = threadIdx.x;
  const int w = tid >> 6, lane = tid & 63;
  const int lr = lane & 15, lg = lane >> 4;
  const int m0 = blockIdx.y * 128;
  const int n0 = blockIdx.x * 128;
  const int wm = (w >> 1) * 64, wn = (w & 1) * 64;

  const int srow = tid >> 2, scol = (tid & 3) * 8;
  const bf16_t* ga = ab + (size_t)(m0 + srow) * C_DIM + scol;
  const bf16_t* gb = wt + (size_t)(n0 + srow) * C_DIM + scol;

  f32x4 acc[4][4];
#pragma unroll
  for (int i = 0; i < 4; i++)
#pragma unroll
    for (int j = 0; j < 4; j++) acc[i][j] = (f32x4){0.f, 0.f, 0.f, 0.f};

  for (int k0 = 0; k0 < C_DIM; k0 += 32) {
    gld_lds16(ga + k0, &lA[tid * 8]);
    gld_lds16(ga + (size_t)64 * C_DIM + k0, &lA[2048 + tid * 8]);
    gld_lds16(gb + k0, &lB[tid * 8]);
    gld_lds16(gb + (size_t)64 * C_DIM + k0, &lB[2048 + tid * 8]);
    __syncthreads();
    bf16x8 a[4], b[4];
#pragma unroll
    for (int mb = 0; mb < 4; mb++)
      a[mb] = *(const bf16x8*)&lA[(wm + mb * 16 + lr) * 32 + lg * 8];
#pragma unroll
    for (int nb = 0; nb < 4; nb++)
      b[nb] = *(const bf16x8*)&lB[(wn + nb * 16 + lr) * 32 + lg * 8];
#pragma unroll
    for (int mb = 0; mb < 4; mb++)
#pragma unroll
      for (int nb = 0; nb < 4; nb++)
        acc[mb][nb] = __builtin_amdgcn_mfma_f32_16x16x32_bf16(a[mb], b[nb], acc[mb][nb], 0, 0, 0);
    __syncthreads();
  }

#pragma unroll
  for (int nb = 0; nb < 4; nb++) {
    const int n = n0 + wn + nb * 16 + lr;
    const float bias = bo[n];
#pragma unroll
    for (int mb = 0; mb < 4; mb++) {
#pragma unroll
      for (int r = 0; r < 4; r++) {
        const int m = m0 + wm + mb * 16 + lg * 4 + r;
        out[(size_t)m * C_DIM + n] = acc[mb][nb][r] + bias;
      }
    }
  }
}

// ---------------------------------------------------------------------------
// launch
// ---------------------------------------------------------------------------
extern "C" void kernel_launch(void* const* d_in, const int* in_sizes, int n_in,
                              void* d_out, int out_size, void* d_ws, size_t ws_size,
                              hipStream_t stream) {
  const float* x  = (const float*)d_in[0];
  const float* wq = (const float*)d_in[2];
  const float* bq = (const float*)d_in[3];
  const float* wk = (const float*)d_in[4];
  const float* bk = (const float*)d_in[5];
  const float* wv = (const float*)d_in[6];
  const float* bv = (const float*)d_in[7];
  const float* wo = (const float*)d_in[8];
  const float* bo = (const float*)d_in[9];

  char* ws = (char*)d_ws;
  bf16_t* xb     = (bf16_t*)(ws);
  bf16_t* wt_qkv = (bf16_t*)(ws + (16ull << 20));
  bf16_t* wt_o   = (bf16_t*)(ws + (22ull << 20));
  bf16_t* qb     = (bf16_t*)(ws + (24ull << 20));
  bf16_t* kb     = (bf16_t*)(ws + (40ull << 20));
  bf16_t* vtb    = (bf16_t*)(ws + (56ull << 20));
  bf16_t* attn_o = xb;  // alias: xb dead after QKV GEMM

  const int n4 = M_TOK * C_DIM / 4;
  msa_cvt_x<<<n4 / 256, 256, 0, stream>>>(x, xb, n4);
  msa_transpose_w<<<dim3(32, 32, 4), 256, 0, stream>>>(wq, wk, wv, wo, wt_qkv, wt_o);
  msa_gemm_qkv<<<dim3(24, 64), 256, 0, stream>>>(xb, wt_qkv, bq, bk, bv, qb, kb, vtb);
  msa_attn32<<<dim3(64, 32), 64, 0, stream>>>(qb, kb, vtb, attn_o);
  msa_gemm_out<<<dim3(8, 64), 256, 0, stream>>>(attn_o, wt_o, bo, (float*)d_out);
}

// Round 8
// 226.959 us; speedup vs baseline: 1.1000x; 1.1000x over previous
//
#include <hip/hip_runtime.h>

typedef __bf16 bf16_t;
typedef bf16_t bf16x8 __attribute__((ext_vector_type(8)));
typedef bf16_t bf16x4 __attribute__((ext_vector_type(4)));
typedef float  f32x4  __attribute__((ext_vector_type(4)));
typedef float  f32x16 __attribute__((ext_vector_type(16)));
typedef unsigned int u32;
typedef u32 u32x2 __attribute__((ext_vector_type(2)));
typedef u32 u32x4 __attribute__((ext_vector_type(4)));

#define T_SEQ 2048
#define C_DIM 1024
#define NH    16
#define DH    64
#define BATCH 4
#define M_TOK (BATCH * T_SEQ)   // 8192

// Q pre-scale: 1/sqrt(64) * log2(e)  -> softmax computed in exp2 domain
#define Q_SCALE 0.1803368801111137f
#define DEFER_THR 8.0f

#define AS1 __attribute__((address_space(1)))
#define AS3 __attribute__((address_space(3)))

__device__ __forceinline__ void gld_lds16(const bf16_t* g, bf16_t* l) {
  __builtin_amdgcn_global_load_lds(
      (const AS1 u32*)(uintptr_t)g,
      (AS3 u32*)(u32)(uintptr_t)l, 16, 0, 0);
}

// v_permlane32_swap_b32: swaps a[32+i] <-> b[i].
__device__ __forceinline__ void plswap(u32& a, u32& b) {
  u32x2 r = __builtin_amdgcn_permlane32_swap(a, b, false, false);
  a = r[0]; b = r[1];
}
__device__ __forceinline__ float xmax32(float x) {
  u32 a = __builtin_bit_cast(u32, x), b = a;
  plswap(a, b);
  return fmaxf(__builtin_bit_cast(float, a), __builtin_bit_cast(float, b));
}
__device__ __forceinline__ float xsum32(float x) {
  u32 a = __builtin_bit_cast(u32, x), b = a;
  plswap(a, b);
  return __builtin_bit_cast(float, a) + __builtin_bit_cast(float, b);
}

// ---------------------------------------------------------------------------
// prep: x f32 -> bf16
// ---------------------------------------------------------------------------
__global__ __launch_bounds__(256) void msa_cvt_x(const float* __restrict__ x,
                                                 bf16_t* __restrict__ xb, int n4) {
  int i = blockIdx.x * 256 + threadIdx.x;
  if (i < n4) {
    const float4 v = ((const float4*)x)[i];
    bf16x4 o;
    o[0] = (bf16_t)v.x; o[1] = (bf16_t)v.y; o[2] = (bf16_t)v.z; o[3] = (bf16_t)v.w;
    ((bf16x4*)xb)[i] = o;
  }
}

// ---------------------------------------------------------------------------
// prep: weight transpose+convert: w[k][n] f32 -> wt[n][k] bf16
// ---------------------------------------------------------------------------
__global__ __launch_bounds__(256) void msa_transpose_w(
    const float* __restrict__ wq, const float* __restrict__ wk,
    const float* __restrict__ wv, const float* __restrict__ wo,
    bf16_t* __restrict__ wt_qkv, bf16_t* __restrict__ wt_o) {
  __shared__ float tile[32][33];
  const int a = blockIdx.z;
  const float* src = (a == 0) ? wq : (a == 1) ? wk : (a == 2) ? wv : wo;
  bf16_t* dst = (a < 3) ? (wt_qkv + (size_t)a * C_DIM * C_DIM) : wt_o;
  const int tx = threadIdx.x & 31, ty = threadIdx.x >> 5;
  const int bi = blockIdx.y * 32, bj = blockIdx.x * 32;
#pragma unroll
  for (int p = 0; p < 4; p++) {
    int r = p * 8 + ty;
    tile[r][tx] = src[(size_t)(bi + r) * C_DIM + bj + tx];
  }
  __syncthreads();
#pragma unroll
  for (int p = 0; p < 4; p++) {
    int r = p * 8 + ty;
    dst[(size_t)(bj + r) * C_DIM + bi + tx] = (bf16_t)tile[tx][r];
  }
}

// ---------------------------------------------------------------------------
// QKV GEMM, m97 structure with BK=64 (two [128][32] sub-tiles per K-step:
// identical LDS layout/read pattern as BK=32, half the barrier count).
// ---------------------------------------------------------------------------
__global__ __launch_bounds__(256) void msa_gemm_qkv(
    const bf16_t* __restrict__ xb, const bf16_t* __restrict__ wt,
    const float* __restrict__ bq, const float* __restrict__ bk,
    const float* __restrict__ bv,
    bf16_t* __restrict__ qo, bf16_t* __restrict__ ko, bf16_t* __restrict__ vto) {
  __shared__ bf16_t lA[2 * 128 * 32];
  __shared__ bf16_t lB[2 * 128 * 32];
  const int tid = threadIdx.x;
  const int w = tid >> 6, lane = tid & 63;
  const int lr = lane & 15, lg = lane >> 4;
  const int m0 = blockIdx.y * 128;
  const int n0 = blockIdx.x * 128;
  const int wm = (w >> 1) * 64, wn = (w & 1) * 64;

  const int srow = tid >> 2, scol = (tid & 3) * 8;
  const bf16_t* ga = xb + (size_t)(m0 + srow) * C_DIM + scol;
  const bf16_t* gb = wt + (size_t)(n0 + srow) * C_DIM + scol;

  f32x4 acc[4][4];
#pragma unroll
  for (int i = 0; i < 4; i++)
#pragma unroll
    for (int j = 0; j < 4; j++) acc[i][j] = (f32x4){0.f, 0.f, 0.f, 0.f};

  for (int k0 = 0; k0 < C_DIM; k0 += 64) {
    // stage two k-subtiles per operand (linear LDS dest, per-lane source)
    gld_lds16(ga + k0, &lA[tid * 8]);
    gld_lds16(ga + (size_t)64 * C_DIM + k0, &lA[2048 + tid * 8]);
    gld_lds16(ga + k0 + 32, &lA[4096 + tid * 8]);
    gld_lds16(ga + (size_t)64 * C_DIM + k0 + 32, &lA[6144 + tid * 8]);
    gld_lds16(gb + k0, &lB[tid * 8]);
    gld_lds16(gb + (size_t)64 * C_DIM + k0, &lB[2048 + tid * 8]);
    gld_lds16(gb + k0 + 32, &lB[4096 + tid * 8]);
    gld_lds16(gb + (size_t)64 * C_DIM + k0 + 32, &lB[6144 + tid * 8]);
    __syncthreads();
#pragma unroll
    for (int h = 0; h < 2; h++) {
      bf16x8 a[4], b[4];
#pragma unroll
      for (int mb = 0; mb < 4; mb++)
        a[mb] = *(const bf16x8*)&lA[h * 4096 + (wm + mb * 16 + lr) * 32 + lg * 8];
#pragma unroll
      for (int nb = 0; nb < 4; nb++)
        b[nb] = *(const bf16x8*)&lB[h * 4096 + (wn + nb * 16 + lr) * 32 + lg * 8];
#pragma unroll
      for (int mb = 0; mb < 4; mb++)
#pragma unroll
        for (int nb = 0; nb < 4; nb++)
          acc[mb][nb] = __builtin_amdgcn_mfma_f32_16x16x32_bf16(a[mb], b[nb], acc[mb][nb], 0, 0, 0);
    }
    __syncthreads();
  }

#pragma unroll
  for (int nb = 0; nb < 4; nb++) {
    const int n = n0 + wn + nb * 16 + lr;
    const int g = n >> 10, c = n & 1023, h = c >> 6, d = c & 63;
    const float bias = (g == 0) ? bq[c] : (g == 1) ? bk[c] : bv[c];
#pragma unroll
    for (int mb = 0; mb < 4; mb++) {
#pragma unroll
      for (int r = 0; r < 4; r++) {
        const int m = m0 + wm + mb * 16 + lg * 4 + r;
        const int bi = m >> 11, t = m & (T_SEQ - 1);
        float v = acc[mb][nb][r] + bias;
        if (g == 0)
          qo[(((size_t)bi * NH + h) * T_SEQ + t) * DH + d] = (bf16_t)(v * Q_SCALE);
        else if (g == 1)
          ko[(((size_t)bi * NH + h) * T_SEQ + t) * DH + d] = (bf16_t)v;
        else
          vto[(((size_t)bi * NH + h) * DH + d) * T_SEQ + t] = (bf16_t)v;
      }
    }
  }
}

// ---------------------------------------------------------------------------
// attn softmax + pack (permlane32_swap: no LDS, no selects)
// ---------------------------------------------------------------------------
__device__ __forceinline__ void sm_pack(f32x16& s, float& m_run, float& l_run,
                                        f32x16& o0, f32x16& o1,
                                        bf16x8& pa0, bf16x8& pa1) {
  float t0 = fmaxf(fmaxf(s[0], s[1]), s[2]);
  float t1 = fmaxf(fmaxf(s[3], s[4]), s[5]);
  float t2 = fmaxf(fmaxf(s[6], s[7]), s[8]);
  float t3 = fmaxf(fmaxf(s[9], s[10]), s[11]);
  float t4 = fmaxf(fmaxf(s[12], s[13]), s[14]);
  float t5 = fmaxf(fmaxf(t0, t1), s[15]);
  float mt = fmaxf(fmaxf(fmaxf(t2, t3), t4), t5);
  mt = xmax32(mt);

  if (__any(mt > m_run + DEFER_THR)) {
    const float mnew = fmaxf(m_run, mt);
    const float al = __builtin_amdgcn_exp2f(m_run - mnew);
    m_run = mnew;
    l_run *= al;
#pragma unroll
    for (int r = 0; r < 16; r++) { o0[r] *= al; o1[r] *= al; }
  }

#pragma unroll
  for (int r = 0; r < 16; r++) s[r] = __builtin_amdgcn_exp2f(s[r] - m_run);
  {
    float a0 = (s[0] + s[1]) + (s[2] + s[3]);
    float a1 = (s[4] + s[5]) + (s[6] + s[7]);
    float a2 = (s[8] + s[9]) + (s[10] + s[11]);
    float a3 = (s[12] + s[13]) + (s[14] + s[15]);
    l_run += xsum32((a0 + a1) + (a2 + a3));
  }

  u32 pk8[8];
#pragma unroll
  for (int i = 0; i < 8; i++) {
    const unsigned short lo = __builtin_bit_cast(unsigned short, (bf16_t)s[2 * i]);
    const unsigned short hh = __builtin_bit_cast(unsigned short, (bf16_t)s[2 * i + 1]);
    pk8[i] = ((u32)hh << 16) | (u32)lo;
  }
  u32 f0w0 = pk8[0], f0w2 = pk8[2];
  u32 f0w1 = pk8[1], f0w3 = pk8[3];
  u32 f1w0 = pk8[4], f1w2 = pk8[6];
  u32 f1w1 = pk8[5], f1w3 = pk8[7];
  plswap(f0w0, f0w2);
  plswap(f0w1, f0w3);
  plswap(f1w0, f1w2);
  plswap(f1w1, f1w3);
  const u32x4 q0v = {f0w0, f0w1, f0w2, f0w3};
  const u32x4 q1v = {f1w0, f1w1, f1w2, f1w3};
  pa0 = __builtin_bit_cast(bf16x8, q0v);
  pa1 = __builtin_bit_cast(bf16x8, q1v);
}

__device__ __forceinline__ void store_o(f32x16& o0, f32x16& o1, float l_fin,
                                        bf16_t* __restrict__ orow, const int hi) {
  const float inv = 1.0f / l_fin;
#pragma unroll
  for (int db = 0; db < 2; db++) {
#pragma unroll
    for (int r = 0; r < 16; r += 2) {
      const int d = db * 32 + (r & 3) + 8 * (r >> 2) + 4 * hi;
      const float v0 = (db ? o1[r] : o0[r]) * inv;
      const float v1 = (db ? o1[r + 1] : o0[r + 1]) * inv;
      const unsigned short b0 = __builtin_bit_cast(unsigned short, (bf16_t)v0);
      const unsigned short b1 = __builtin_bit_cast(unsigned short, (bf16_t)v1);
      *reinterpret_cast<u32*>(orow + d) = ((u32)b1 << 16) | (u32)b0;
    }
  }
}

// ---------------------------------------------------------------------------
// Flash attention (causal): R4 structure (best measured: 109.5us).
// Dual-stream pairs, 1 wave per block, K ping-pong prefetch one tile ahead,
// V loaded in the consuming iteration, permlane-based softmax/pack, no LDS.
// Grid (bh=64, pair=32).
// ---------------------------------------------------------------------------
__global__ __launch_bounds__(64, 2) void msa_attn32(
    const bf16_t* __restrict__ Q, const bf16_t* __restrict__ K,
    const bf16_t* __restrict__ Vt, bf16_t* __restrict__ O) {
  const int lane = threadIdx.x;
  const int l31 = lane & 31;
  const int hi = lane >> 5;
  const int bh = blockIdx.x;
  const int p = blockIdx.y;
  const int tS = p, tL = 63 - p;
  const int q0S = tS * 32, q0L = tL * 32;

  const bf16_t* Qh = Q + (size_t)bh * T_SEQ * DH;
  const bf16_t* Kh = K + (size_t)bh * T_SEQ * DH;
  const bf16_t* Vh = Vt + (size_t)bh * DH * T_SEQ;

  bf16x8 qfL[4], qfS[4];
#pragma unroll
  for (int dc = 0; dc < 4; dc++) {
    qfL[dc] = *(const bf16x8*)(Qh + (size_t)(q0L + l31) * DH + dc * 16 + hi * 8);
    qfS[dc] = *(const bf16x8*)(Qh + (size_t)(q0S + l31) * DH + dc * 16 + hi * 8);
  }

  f32x16 oL0, oL1, oS0, oS1;
#pragma unroll
  for (int r = 0; r < 16; r++) { oL0[r] = 0.f; oL1[r] = 0.f; oS0[r] = 0.f; oS1[r] = 0.f; }
  float mL = -1e30f, lL = 0.f, mS = -1e30f, lS = 0.f;
  const f32x16 z16 = {};

  // preload K tile 0
  bf16x8 kA[4], kB[4];
#pragma unroll
  for (int dc = 0; dc < 4; dc++)
    kA[dc] = *(const bf16x8*)(Kh + (size_t)l31 * DH + dc * 16 + hi * 8);

  int kt = 0;

  // body: compute tile kt with KC; prefetch K tile kt+1 into KN; V same-iter
#define ATTN_BODY(KC, KN)                                                          \
  {                                                                                \
    const int j0 = kt * 32;                                                        \
    const int jn = (kt < tL) ? j0 + 32 : 0;                                        \
    _Pragma("unroll") for (int dc = 0; dc < 4; dc++)                               \
        KN[dc] = *(const bf16x8*)(Kh + (size_t)(jn + l31) * DH + dc * 16 + hi * 8);\
    const bf16x8 vf00 = *(const bf16x8*)(Vh + (size_t)l31 * T_SEQ + j0 + hi * 8);  \
    const bf16x8 vf01 = *(const bf16x8*)(Vh + (size_t)l31 * T_SEQ + j0 + 16 + hi * 8); \
    const bf16x8 vf10 = *(const bf16x8*)(Vh + (size_t)(32 + l31) * T_SEQ + j0 + hi * 8); \
    const bf16x8 vf11 = *(const bf16x8*)(Vh + (size_t)(32 + l31) * T_SEQ + j0 + 16 + hi * 8); \
    const bool actS = (kt <= tS);                                                  \
    f32x16 sL = __builtin_amdgcn_mfma_f32_32x32x16_bf16(KC[0], qfL[0], z16, 0, 0, 0); \
    _Pragma("unroll") for (int dc = 1; dc < 4; dc++)                               \
        sL = __builtin_amdgcn_mfma_f32_32x32x16_bf16(KC[dc], qfL[dc], sL, 0, 0, 0);\
    f32x16 sS;                                                                     \
    if (actS) {                                                                    \
      sS = __builtin_amdgcn_mfma_f32_32x32x16_bf16(KC[0], qfS[0], z16, 0, 0, 0);   \
      _Pragma("unroll") for (int dc = 1; dc < 4; dc++)                             \
          sS = __builtin_amdgcn_mfma_f32_32x32x16_bf16(KC[dc], qfS[dc], sS, 0, 0, 0); \
    }                                                                              \
    if (kt == tL) {                                                                \
      _Pragma("unroll") for (int r = 0; r < 16; r++) {                             \
        const int jrow = (r & 3) + 8 * (r >> 2) + 4 * hi;                          \
        if (jrow > l31) sL[r] = -1e30f;                                            \
      }                                                                            \
    }                                                                              \
    if (kt == tS) {                                                                \
      _Pragma("unroll") for (int r = 0; r < 16; r++) {                             \
        const int jrow = (r & 3) + 8 * (r >> 2) + 4 * hi;                          \
        if (jrow > l31) sS[r] = -1e30f;                                            \
      }                                                                            \
    }                                                                              \
    bf16x8 paL0, paL1;                                                             \
    sm_pack(sL, mL, lL, oL0, oL1, paL0, paL1);                                     \
    oL0 = __builtin_amdgcn_mfma_f32_32x32x16_bf16(vf00, paL0, oL0, 0, 0, 0);       \
    oL1 = __builtin_amdgcn_mfma_f32_32x32x16_bf16(vf10, paL0, oL1, 0, 0, 0);       \
    oL0 = __builtin_amdgcn_mfma_f32_32x32x16_bf16(vf01, paL1, oL0, 0, 0, 0);       \
    oL1 = __builtin_amdgcn_mfma_f32_32x32x16_bf16(vf11, paL1, oL1, 0, 0, 0);       \
    if (actS) {                                                                    \
      bf16x8 paS0, paS1;                                                           \
      sm_pack(sS, mS, lS, oS0, oS1, paS0, paS1);                                   \
      oS0 = __builtin_amdgcn_mfma_f32_32x32x16_bf16(vf00, paS0, oS0, 0, 0, 0);     \
      oS1 = __builtin_amdgcn_mfma_f32_32x32x16_bf16(vf10, paS0, oS1, 0, 0, 0);     \
      oS0 = __builtin_amdgcn_mfma_f32_32x32x16_bf16(vf01, paS1, oS0, 0, 0, 0);     \
      oS1 = __builtin_amdgcn_mfma_f32_32x32x16_bf16(vf11, paS1, oS1, 0, 0, 0);     \
    }                                                                              \
  }

  while (kt <= tL) {
    ATTN_BODY(kA, kB);
    kt++;
    if (kt > tL) break;
    ATTN_BODY(kB, kA);
    kt++;
  }
#undef ATTN_BODY

  const int b = bh >> 4, h = bh & 15;
  store_o(oL0, oL1, lL, O + ((size_t)b * T_SEQ + q0L + l31) * C_DIM + h * DH, hi);
  store_o(oS0, oS1, lS, O + ((size_t)b * T_SEQ + q0S + l31) * C_DIM + h * DH, hi);
}

// ---------------------------------------------------------------------------
// Output projection, m97 structure with BK=64
// ---------------------------------------------------------------------------
__global__ __launch_bounds__(256) void msa_gemm_out(
    const bf16_t* __restrict__ ab, const bf16_t* __restrict__ wt,
    const float* __restrict__ bo, float* __restrict__ out) {
  __shared__ bf16_t lA[2 * 128 * 32];
  __shared__ bf16_t lB[2 * 128 * 32];
  const int tid = threadIdx.x;
  const int w = tid >> 6, lane = tid & 63;
  const int lr = lane & 15, lg = lane >> 4;
  const int m0 = blockIdx.y * 128;
  const int n0 = blockIdx.x * 128;
  const int wm = (w >> 1) * 64, wn = (w & 1) * 64;

  const int srow = tid >> 2, scol = (tid & 3) * 8;
  const bf16_t* ga = ab + (size_t)(m0 + srow) * C_DIM + scol;
  const bf16_t* gb = wt + (size_t)(n0 + srow) * C_DIM + scol;

  f32x4 acc[4][4];
#pragma unroll
  for (int i = 0; i < 4; i++)
#pragma unroll
    for (int j = 0; j < 4; j++) acc[i][j] = (f32x4){0.f, 0.f, 0.f, 0.f};

  for (int k0 = 0; k0 < C_DIM; k0 += 64) {
    gld_lds16(ga + k0, &lA[tid * 8]);
    gld_lds16(ga + (size_t)64 * C_DIM + k0, &lA[2048 + tid * 8]);
    gld_lds16(ga + k0 + 32, &lA[4096 + tid * 8]);
    gld_lds16(ga + (size_t)64 * C_DIM + k0 + 32, &lA[6144 + tid * 8]);
    gld_lds16(gb + k0, &lB[tid * 8]);
    gld_lds16(gb + (size_t)64 * C_DIM + k0, &lB[2048 + tid * 8]);
    gld_lds16(gb + k0 + 32, &lB[4096 + tid * 8]);
    gld_lds16(gb + (size_t)64 * C_DIM + k0 + 32, &lB[6144 + tid * 8]);
    __syncthreads();
#pragma unroll
    for (int h = 0; h < 2; h++) {
      bf16x8 a[4], b[4];
#pragma unroll
      for (int mb = 0; mb < 4; mb++)
        a[mb] = *(const bf16x8*)&lA[h * 4096 + (wm + mb * 16 + lr) * 32 + lg * 8];
#pragma unroll
      for (int nb = 0; nb < 4; nb++)
        b[nb] = *(const bf16x8*)&lB[h * 4096 + (wn + nb * 16 + lr) * 32 + lg * 8];
#pragma unroll
      for (int mb = 0; mb < 4; mb++)
#pragma unroll
        for (int nb = 0; nb < 4; nb++)
          acc[mb][nb] = __builtin_amdgcn_mfma_f32_16x16x32_bf16(a[mb], b[nb], acc[mb][nb], 0, 0, 0);
    }
    __syncthreads();
  }

#pragma unroll
  for (int nb = 0; nb < 4; nb++) {
    const int n = n0 + wn + nb * 16 + lr;
    const float bias = bo[n];
#pragma unroll
    for (int mb = 0; mb < 4; mb++) {
#pragma unroll
      for (int r = 0; r < 4; r++) {
        const int m = m0 + wm + mb * 16 + lg * 4 + r;
        out[(size_t)m * C_DIM + n] = acc[mb][nb][r] + bias;
      }
    }
  }
}

// ---------------------------------------------------------------------------
// launch
// ---------------------------------------------------------------------------
extern "C" void kernel_launch(void* const* d_in, const int* in_sizes, int n_in,
                              void* d_out, int out_size, void* d_ws, size_t ws_size,
                              hipStream_t stream) {
  const float* x  = (const float*)d_in[0];
  const float* wq = (const float*)d_in[2];
  const float* bq = (const float*)d_in[3];
  const float* wk = (const float*)d_in[4];
  const float* bk = (const float*)d_in[5];
  const float* wv = (const float*)d_in[6];
  const float* bv = (const float*)d_in[7];
  const float* wo = (const float*)d_in[8];
  const float* bo = (const float*)d_in[9];

  char* ws = (char*)d_ws;
  bf16_t* xb     = (bf16_t*)(ws);
  bf16_t* wt_qkv = (bf16_t*)(ws + (16ull << 20));
  bf16_t* wt_o   = (bf16_t*)(ws + (22ull << 20));
  bf16_t* qb     = (bf16_t*)(ws + (24ull << 20));
  bf16_t* kb     = (bf16_t*)(ws + (40ull << 20));
  bf16_t* vtb    = (bf16_t*)(ws + (56ull << 20));
  bf16_t* attn_o = xb;  // alias: xb dead after QKV GEMM

  const int n4 = M_TOK * C_DIM / 4;
  msa_cvt_x<<<n4 / 256, 256, 0, stream>>>(x, xb, n4);
  msa_transpose_w<<<dim3(32, 32, 4), 256, 0, stream>>>(wq, wk, wv, wo, wt_qkv, wt_o);
  msa_gemm_qkv<<<dim3(24, 64), 256, 0, stream>>>(xb, wt_qkv, bq, bk, bv, qb, kb, vtb);
  msa_attn32<<<dim3(64, 32), 64, 0, stream>>>(qb, kb, vtb, attn_o);
  msa_gemm_out<<<dim3(8, 64), 256, 0, stream>>>(attn_o, wt_o, bo, (float*)d_out);
}

// Round 9
// 226.205 us; speedup vs baseline: 1.1037x; 1.0033x over previous
//
#include <hip/hip_runtime.h>

typedef __bf16 bf16_t;
typedef bf16_t bf16x8 __attribute__((ext_vector_type(8)));
typedef bf16_t bf16x4 __attribute__((ext_vector_type(4)));
typedef float  f32x4  __attribute__((ext_vector_type(4)));
typedef float  f32x16 __attribute__((ext_vector_type(16)));
typedef unsigned int u32;
typedef u32 u32x2 __attribute__((ext_vector_type(2)));
typedef u32 u32x4 __attribute__((ext_vector_type(4)));

#define T_SEQ 2048
#define C_DIM 1024
#define NH    16
#define DH    64
#define BATCH 4
#define M_TOK (BATCH * T_SEQ)   // 8192

// Q pre-scale: 1/sqrt(64) * log2(e)  -> softmax computed in exp2 domain
#define Q_SCALE 0.1803368801111137f
#define DEFER_THR 8.0f

#define AS1 __attribute__((address_space(1)))
#define AS3 __attribute__((address_space(3)))

__device__ __forceinline__ void gld_lds16(const bf16_t* g, bf16_t* l) {
  __builtin_amdgcn_global_load_lds(
      (const AS1 u32*)(uintptr_t)g,
      (AS3 u32*)(u32)(uintptr_t)l, 16, 0, 0);
}

// v_permlane32_swap_b32: swaps a[32+i] <-> b[i].
__device__ __forceinline__ void plswap(u32& a, u32& b) {
  u32x2 r = __builtin_amdgcn_permlane32_swap(a, b, false, false);
  a = r[0]; b = r[1];
}
__device__ __forceinline__ float xmax32(float x) {
  u32 a = __builtin_bit_cast(u32, x), b = a;
  plswap(a, b);
  return fmaxf(__builtin_bit_cast(float, a), __builtin_bit_cast(float, b));
}
__device__ __forceinline__ float xsum32(float x) {
  u32 a = __builtin_bit_cast(u32, x), b = a;
  plswap(a, b);
  return __builtin_bit_cast(float, a) + __builtin_bit_cast(float, b);
}

// ---------------------------------------------------------------------------
// prep: x f32 -> bf16
// ---------------------------------------------------------------------------
__global__ __launch_bounds__(256) void msa_cvt_x(const float* __restrict__ x,
                                                 bf16_t* __restrict__ xb, int n4) {
  int i = blockIdx.x * 256 + threadIdx.x;
  if (i < n4) {
    const float4 v = ((const float4*)x)[i];
    bf16x4 o;
    o[0] = (bf16_t)v.x; o[1] = (bf16_t)v.y; o[2] = (bf16_t)v.z; o[3] = (bf16_t)v.w;
    ((bf16x4*)xb)[i] = o;
  }
}

// ---------------------------------------------------------------------------
// prep: weight transpose+convert: w[k][n] f32 -> wt[n][k] bf16
// ---------------------------------------------------------------------------
__global__ __launch_bounds__(256) void msa_transpose_w(
    const float* __restrict__ wq, const float* __restrict__ wk,
    const float* __restrict__ wv, const float* __restrict__ wo,
    bf16_t* __restrict__ wt_qkv, bf16_t* __restrict__ wt_o) {
  __shared__ float tile[32][33];
  const int a = blockIdx.z;
  const float* src = (a == 0) ? wq : (a == 1) ? wk : (a == 2) ? wv : wo;
  bf16_t* dst = (a < 3) ? (wt_qkv + (size_t)a * C_DIM * C_DIM) : wt_o;
  const int tx = threadIdx.x & 31, ty = threadIdx.x >> 5;
  const int bi = blockIdx.y * 32, bj = blockIdx.x * 32;
#pragma unroll
  for (int p = 0; p < 4; p++) {
    int r = p * 8 + ty;
    tile[r][tx] = src[(size_t)(bi + r) * C_DIM + bj + tx];
  }
  __syncthreads();
#pragma unroll
  for (int p = 0; p < 4; p++) {
    int r = p * 8 + ty;
    dst[(size_t)(bj + r) * C_DIM + bi + tx] = (bf16_t)tile[tx][r];
  }
}

// ---------------------------------------------------------------------------
// QKV GEMM, m97 structure with BK=64
// ---------------------------------------------------------------------------
__global__ __launch_bounds__(256) void msa_gemm_qkv(
    const bf16_t* __restrict__ xb, const bf16_t* __restrict__ wt,
    const float* __restrict__ bq, const float* __restrict__ bk,
    const float* __restrict__ bv,
    bf16_t* __restrict__ qo, bf16_t* __restrict__ ko, bf16_t* __restrict__ vto) {
  __shared__ bf16_t lA[2 * 128 * 32];
  __shared__ bf16_t lB[2 * 128 * 32];
  const int tid = threadIdx.x;
  const int w = tid >> 6, lane = tid & 63;
  const int lr = lane & 15, lg = lane >> 4;
  const int m0 = blockIdx.y * 128;
  const int n0 = blockIdx.x * 128;
  const int wm = (w >> 1) * 64, wn = (w & 1) * 64;

  const int srow = tid >> 2, scol = (tid & 3) * 8;
  const bf16_t* ga = xb + (size_t)(m0 + srow) * C_DIM + scol;
  const bf16_t* gb = wt + (size_t)(n0 + srow) * C_DIM + scol;

  f32x4 acc[4][4];
#pragma unroll
  for (int i = 0; i < 4; i++)
#pragma unroll
    for (int j = 0; j < 4; j++) acc[i][j] = (f32x4){0.f, 0.f, 0.f, 0.f};

  for (int k0 = 0; k0 < C_DIM; k0 += 64) {
    gld_lds16(ga + k0, &lA[tid * 8]);
    gld_lds16(ga + (size_t)64 * C_DIM + k0, &lA[2048 + tid * 8]);
    gld_lds16(ga + k0 + 32, &lA[4096 + tid * 8]);
    gld_lds16(ga + (size_t)64 * C_DIM + k0 + 32, &lA[6144 + tid * 8]);
    gld_lds16(gb + k0, &lB[tid * 8]);
    gld_lds16(gb + (size_t)64 * C_DIM + k0, &lB[2048 + tid * 8]);
    gld_lds16(gb + k0 + 32, &lB[4096 + tid * 8]);
    gld_lds16(gb + (size_t)64 * C_DIM + k0 + 32, &lB[6144 + tid * 8]);
    __syncthreads();
#pragma unroll
    for (int h = 0; h < 2; h++) {
      bf16x8 a[4], b[4];
#pragma unroll
      for (int mb = 0; mb < 4; mb++)
        a[mb] = *(const bf16x8*)&lA[h * 4096 + (wm + mb * 16 + lr) * 32 + lg * 8];
#pragma unroll
      for (int nb = 0; nb < 4; nb++)
        b[nb] = *(const bf16x8*)&lB[h * 4096 + (wn + nb * 16 + lr) * 32 + lg * 8];
#pragma unroll
      for (int mb = 0; mb < 4; mb++)
#pragma unroll
        for (int nb = 0; nb < 4; nb++)
          acc[mb][nb] = __builtin_amdgcn_mfma_f32_16x16x32_bf16(a[mb], b[nb], acc[mb][nb], 0, 0, 0);
    }
    __syncthreads();
  }

#pragma unroll
  for (int nb = 0; nb < 4; nb++) {
    const int n = n0 + wn + nb * 16 + lr;
    const int g = n >> 10, c = n & 1023, h = c >> 6, d = c & 63;
    const float bias = (g == 0) ? bq[c] : (g == 1) ? bk[c] : bv[c];
#pragma unroll
    for (int mb = 0; mb < 4; mb++) {
#pragma unroll
      for (int r = 0; r < 4; r++) {
        const int m = m0 + wm + mb * 16 + lg * 4 + r;
        const int bi = m >> 11, t = m & (T_SEQ - 1);
        float v = acc[mb][nb][r] + bias;
        if (g == 0)
          qo[(((size_t)bi * NH + h) * T_SEQ + t) * DH + d] = (bf16_t)(v * Q_SCALE);
        else if (g == 1)
          ko[(((size_t)bi * NH + h) * T_SEQ + t) * DH + d] = (bf16_t)v;
        else
          vto[(((size_t)bi * NH + h) * DH + d) * T_SEQ + t] = (bf16_t)v;
      }
    }
  }
}

// ---------------------------------------------------------------------------
// attn: softmax + pack for one 32-key tile (permlane, no LDS)
// ---------------------------------------------------------------------------
__device__ __forceinline__ void pack_frag(const f32x16& s, bf16x8& pa0, bf16x8& pa1) {
  u32 pk8[8];
#pragma unroll
  for (int i = 0; i < 8; i++) {
    const unsigned short lo = __builtin_bit_cast(unsigned short, (bf16_t)s[2 * i]);
    const unsigned short hh = __builtin_bit_cast(unsigned short, (bf16_t)s[2 * i + 1]);
    pk8[i] = ((u32)hh << 16) | (u32)lo;
  }
  u32 f0w0 = pk8[0], f0w2 = pk8[2];
  u32 f0w1 = pk8[1], f0w3 = pk8[3];
  u32 f1w0 = pk8[4], f1w2 = pk8[6];
  u32 f1w1 = pk8[5], f1w3 = pk8[7];
  plswap(f0w0, f0w2);
  plswap(f0w1, f0w3);
  plswap(f1w0, f1w2);
  plswap(f1w1, f1w3);
  const u32x4 q0v = {f0w0, f0w1, f0w2, f0w3};
  const u32x4 q1v = {f1w0, f1w1, f1w2, f1w3};
  pa0 = __builtin_bit_cast(bf16x8, q0v);
  pa1 = __builtin_bit_cast(bf16x8, q1v);
}

__device__ __forceinline__ void sm_pack(f32x16& s, float& m_run, float& l_run,
                                        f32x16& o0, f32x16& o1,
                                        bf16x8& pa0, bf16x8& pa1) {
  float t0 = fmaxf(fmaxf(s[0], s[1]), s[2]);
  float t1 = fmaxf(fmaxf(s[3], s[4]), s[5]);
  float t2 = fmaxf(fmaxf(s[6], s[7]), s[8]);
  float t3 = fmaxf(fmaxf(s[9], s[10]), s[11]);
  float t4 = fmaxf(fmaxf(s[12], s[13]), s[14]);
  float t5 = fmaxf(fmaxf(t0, t1), s[15]);
  float mt = fmaxf(fmaxf(fmaxf(t2, t3), t4), t5);
  mt = xmax32(mt);

  if (__any(mt > m_run + DEFER_THR)) {
    const float mnew = fmaxf(m_run, mt);
    const float al = __builtin_amdgcn_exp2f(m_run - mnew);
    m_run = mnew;
    l_run *= al;
#pragma unroll
    for (int r = 0; r < 16; r++) { o0[r] *= al; o1[r] *= al; }
  }

#pragma unroll
  for (int r = 0; r < 16; r++) s[r] = __builtin_amdgcn_exp2f(s[r] - m_run);
  {
    float a0 = (s[0] + s[1]) + (s[2] + s[3]);
    float a1 = (s[4] + s[5]) + (s[6] + s[7]);
    float a2 = (s[8] + s[9]) + (s[10] + s[11]);
    float a3 = (s[12] + s[13]) + (s[14] + s[15]);
    l_run += xsum32((a0 + a1) + (a2 + a3));
  }
  pack_frag(s, pa0, pa1);
}

// combined softmax over TWO 32-key tiles (one max/defer/rescale/sum pass)
__device__ __forceinline__ void sm_pack64(f32x16& s0, f32x16& s1,
                                          float& m_run, float& l_run,
                                          f32x16& o0, f32x16& o1,
                                          bf16x8& a0, bf16x8& a1,
                                          bf16x8& b0, bf16x8& b1) {
  float t[8];
#pragma unroll
  for (int i = 0; i < 8; i++)
    t[i] = fmaxf(fmaxf(s0[2 * i], s0[2 * i + 1]), fmaxf(s1[2 * i], s1[2 * i + 1]));
  float u0 = fmaxf(fmaxf(t[0], t[1]), t[2]);
  float u1 = fmaxf(fmaxf(t[3], t[4]), t[5]);
  float mt = fmaxf(fmaxf(fmaxf(t[6], t[7]), u0), u1);
  mt = xmax32(mt);

  if (__any(mt > m_run + DEFER_THR)) {
    const float mnew = fmaxf(m_run, mt);
    const float al = __builtin_amdgcn_exp2f(m_run - mnew);
    m_run = mnew;
    l_run *= al;
#pragma unroll
    for (int r = 0; r < 16; r++) { o0[r] *= al; o1[r] *= al; }
  }

#pragma unroll
  for (int r = 0; r < 16; r++) {
    s0[r] = __builtin_amdgcn_exp2f(s0[r] - m_run);
    s1[r] = __builtin_amdgcn_exp2f(s1[r] - m_run);
  }
  {
    float a = 0.f, b = 0.f;
#pragma unroll
    for (int r = 0; r < 16; r += 4) {
      a += (s0[r] + s0[r + 1]) + (s0[r + 2] + s0[r + 3]);
      b += (s1[r] + s1[r + 1]) + (s1[r + 2] + s1[r + 3]);
    }
    l_run += xsum32(a + b);
  }
  pack_frag(s0, a0, a1);
  pack_frag(s1, b0, b1);
}

__device__ __forceinline__ void store_o(f32x16& o0, f32x16& o1, float l_fin,
                                        bf16_t* __restrict__ orow, const int hi) {
  const float inv = 1.0f / l_fin;
#pragma unroll
  for (int db = 0; db < 2; db++) {
#pragma unroll
    for (int r = 0; r < 16; r += 2) {
      const int d = db * 32 + (r & 3) + 8 * (r >> 2) + 4 * hi;
      const float v0 = (db ? o1[r] : o0[r]) * inv;
      const float v1 = (db ? o1[r + 1] : o0[r + 1]) * inv;
      const unsigned short b0 = __builtin_bit_cast(unsigned short, (bf16_t)v0);
      const unsigned short b1 = __builtin_bit_cast(unsigned short, (bf16_t)v1);
      *reinterpret_cast<u32*>(orow + d) = ((u32)b1 << 16) | (u32)b0;
    }
  }
}

// ---------------------------------------------------------------------------
// Flash attention (causal): equal-slot schedule — every wave runs exactly 33
// slots. Phase 1 (kt=0..p): dual-stream slots sharing the K/V tile (streams
// tL=63-p and tS=p, S masked at kt=p). Phase 2: L-only, 64 keys per slot
// (two K-tiles, ONE combined softmax), diagonal tile tL alone in the final
// masked slot. Removes the 64-vs-33 slot imbalance that set the R4/R8 wall.
// Grid (bh=64, pair=32), 1 wave per block, no LDS.
// ---------------------------------------------------------------------------
__global__ __launch_bounds__(64, 2) void msa_attn32(
    const bf16_t* __restrict__ Q, const bf16_t* __restrict__ K,
    const bf16_t* __restrict__ Vt, bf16_t* __restrict__ O) {
  const int lane = threadIdx.x;
  const int l31 = lane & 31;
  const int hi = lane >> 5;
  const int bh = blockIdx.x;
  const int p = blockIdx.y;
  const int tS = p, tL = 63 - p;
  const int q0S = tS * 32, q0L = tL * 32;

  const bf16_t* Qh = Q + (size_t)bh * T_SEQ * DH;
  const bf16_t* Kh = K + (size_t)bh * T_SEQ * DH;
  const bf16_t* Vh = Vt + (size_t)bh * DH * T_SEQ;

  bf16x8 qfL[4], qfS[4];
#pragma unroll
  for (int dc = 0; dc < 4; dc++) {
    qfL[dc] = *(const bf16x8*)(Qh + (size_t)(q0L + l31) * DH + dc * 16 + hi * 8);
    qfS[dc] = *(const bf16x8*)(Qh + (size_t)(q0S + l31) * DH + dc * 16 + hi * 8);
  }

  f32x16 oL0, oL1, oS0, oS1;
#pragma unroll
  for (int r = 0; r < 16; r++) { oL0[r] = 0.f; oL1[r] = 0.f; oS0[r] = 0.f; oS1[r] = 0.f; }
  float mL = -1e30f, lL = 0.f, mS = -1e30f, lS = 0.f;
  const f32x16 z16 = {};

  // ---------------- Phase 1: dual slots, shared K/V tile (kt = 0..tS) -----
  for (int kt = 0; kt <= tS; ++kt) {
    const int j0 = kt * 32;
    bf16x8 kf[4];
#pragma unroll
    for (int dc = 0; dc < 4; dc++)
      kf[dc] = *(const bf16x8*)(Kh + (size_t)(j0 + l31) * DH + dc * 16 + hi * 8);
    const bf16x8 vf00 = *(const bf16x8*)(Vh + (size_t)l31 * T_SEQ + j0 + hi * 8);
    const bf16x8 vf01 = *(const bf16x8*)(Vh + (size_t)l31 * T_SEQ + j0 + 16 + hi * 8);
    const bf16x8 vf10 = *(const bf16x8*)(Vh + (size_t)(32 + l31) * T_SEQ + j0 + hi * 8);
    const bf16x8 vf11 = *(const bf16x8*)(Vh + (size_t)(32 + l31) * T_SEQ + j0 + 16 + hi * 8);

    f32x16 sL = __builtin_amdgcn_mfma_f32_32x32x16_bf16(kf[0], qfL[0], z16, 0, 0, 0);
    f32x16 sS = __builtin_amdgcn_mfma_f32_32x32x16_bf16(kf[0], qfS[0], z16, 0, 0, 0);
#pragma unroll
    for (int dc = 1; dc < 4; dc++) {
      sL = __builtin_amdgcn_mfma_f32_32x32x16_bf16(kf[dc], qfL[dc], sL, 0, 0, 0);
      sS = __builtin_amdgcn_mfma_f32_32x32x16_bf16(kf[dc], qfS[dc], sS, 0, 0, 0);
    }
    if (kt == tS) {
#pragma unroll
      for (int r = 0; r < 16; r++) {
        const int jrow = (r & 3) + 8 * (r >> 2) + 4 * hi;
        if (jrow > l31) sS[r] = -1e30f;
      }
    }
    bf16x8 paL0, paL1, paS0, paS1;
    sm_pack(sL, mL, lL, oL0, oL1, paL0, paL1);
    sm_pack(sS, mS, lS, oS0, oS1, paS0, paS1);
    oL0 = __builtin_amdgcn_mfma_f32_32x32x16_bf16(vf00, paL0, oL0, 0, 0, 0);
    oL1 = __builtin_amdgcn_mfma_f32_32x32x16_bf16(vf10, paL0, oL1, 0, 0, 0);
    oS0 = __builtin_amdgcn_mfma_f32_32x32x16_bf16(vf00, paS0, oS0, 0, 0, 0);
    oS1 = __builtin_amdgcn_mfma_f32_32x32x16_bf16(vf10, paS0, oS1, 0, 0, 0);
    oL0 = __builtin_amdgcn_mfma_f32_32x32x16_bf16(vf01, paL1, oL0, 0, 0, 0);
    oL1 = __builtin_amdgcn_mfma_f32_32x32x16_bf16(vf11, paL1, oL1, 0, 0, 0);
    oS0 = __builtin_amdgcn_mfma_f32_32x32x16_bf16(vf01, paS1, oS0, 0, 0, 0);
    oS1 = __builtin_amdgcn_mfma_f32_32x32x16_bf16(vf11, paS1, oS1, 0, 0, 0);
  }

  // ---------------- Phase 2: L-only, 64 keys per slot ----------------------
  int j = tS + 1;
  for (; j + 1 < tL; j += 2) {
    const int j0 = j * 32, j1 = j0 + 32;
    bf16x8 k0[4], k1[4];
#pragma unroll
    for (int dc = 0; dc < 4; dc++) {
      k0[dc] = *(const bf16x8*)(Kh + (size_t)(j0 + l31) * DH + dc * 16 + hi * 8);
      k1[dc] = *(const bf16x8*)(Kh + (size_t)(j1 + l31) * DH + dc * 16 + hi * 8);
    }
    const bf16x8 va00 = *(const bf16x8*)(Vh + (size_t)l31 * T_SEQ + j0 + hi * 8);
    const bf16x8 va01 = *(const bf16x8*)(Vh + (size_t)l31 * T_SEQ + j0 + 16 + hi * 8);
    const bf16x8 va10 = *(const bf16x8*)(Vh + (size_t)(32 + l31) * T_SEQ + j0 + hi * 8);
    const bf16x8 va11 = *(const bf16x8*)(Vh + (size_t)(32 + l31) * T_SEQ + j0 + 16 + hi * 8);
    const bf16x8 vb00 = *(const bf16x8*)(Vh + (size_t)l31 * T_SEQ + j1 + hi * 8);
    const bf16x8 vb01 = *(const bf16x8*)(Vh + (size_t)l31 * T_SEQ + j1 + 16 + hi * 8);
    const bf16x8 vb10 = *(const bf16x8*)(Vh + (size_t)(32 + l31) * T_SEQ + j1 + hi * 8);
    const bf16x8 vb11 = *(const bf16x8*)(Vh + (size_t)(32 + l31) * T_SEQ + j1 + 16 + hi * 8);

    f32x16 s0 = __builtin_amdgcn_mfma_f32_32x32x16_bf16(k0[0], qfL[0], z16, 0, 0, 0);
    f32x16 s1 = __builtin_amdgcn_mfma_f32_32x32x16_bf16(k1[0], qfL[0], z16, 0, 0, 0);
#pragma unroll
    for (int dc = 1; dc < 4; dc++) {
      s0 = __builtin_amdgcn_mfma_f32_32x32x16_bf16(k0[dc], qfL[dc], s0, 0, 0, 0);
      s1 = __builtin_amdgcn_mfma_f32_32x32x16_bf16(k1[dc], qfL[dc], s1, 0, 0, 0);
    }
    bf16x8 a0, a1, b0, b1;
    sm_pack64(s0, s1, mL, lL, oL0, oL1, a0, a1, b0, b1);
    oL0 = __builtin_amdgcn_mfma_f32_32x32x16_bf16(va00, a0, oL0, 0, 0, 0);
    oL1 = __builtin_amdgcn_mfma_f32_32x32x16_bf16(va10, a0, oL1, 0, 0, 0);
    oL0 = __builtin_amdgcn_mfma_f32_32x32x16_bf16(va01, a1, oL0, 0, 0, 0);
    oL1 = __builtin_amdgcn_mfma_f32_32x32x16_bf16(va11, a1, oL1, 0, 0, 0);
    oL0 = __builtin_amdgcn_mfma_f32_32x32x16_bf16(vb00, b0, oL0, 0, 0, 0);
    oL1 = __builtin_amdgcn_mfma_f32_32x32x16_bf16(vb10, b0, oL1, 0, 0, 0);
    oL0 = __builtin_amdgcn_mfma_f32_32x32x16_bf16(vb01, b1, oL0, 0, 0, 0);
    oL1 = __builtin_amdgcn_mfma_f32_32x32x16_bf16(vb11, b1, oL1, 0, 0, 0);
  }

  // ---------------- Final slot: diagonal tile tL (masked) ------------------
  {
    const int j0 = tL * 32;
    bf16x8 kf[4];
#pragma unroll
    for (int dc = 0; dc < 4; dc++)
      kf[dc] = *(const bf16x8*)(Kh + (size_t)(j0 + l31) * DH + dc * 16 + hi * 8);
    const bf16x8 vf00 = *(const bf16x8*)(Vh + (size_t)l31 * T_SEQ + j0 + hi * 8);
    const bf16x8 vf01 = *(const bf16x8*)(Vh + (size_t)l31 * T_SEQ + j0 + 16 + hi * 8);
    const bf16x8 vf10 = *(const bf16x8*)(Vh + (size_t)(32 + l31) * T_SEQ + j0 + hi * 8);
    const bf16x8 vf11 = *(const bf16x8*)(Vh + (size_t)(32 + l31) * T_SEQ + j0 + 16 + hi * 8);

    f32x16 sL = __builtin_amdgcn_mfma_f32_32x32x16_bf16(kf[0], qfL[0], z16, 0, 0, 0);
#pragma unroll
    for (int dc = 1; dc < 4; dc++)
      sL = __builtin_amdgcn_mfma_f32_32x32x16_bf16(kf[dc], qfL[dc], sL, 0, 0, 0);
#pragma unroll
    for (int r = 0; r < 16; r++) {
      const int jrow = (r & 3) + 8 * (r >> 2) + 4 * hi;
      if (jrow > l31) sL[r] = -1e30f;
    }
    bf16x8 paL0, paL1;
    sm_pack(sL, mL, lL, oL0, oL1, paL0, paL1);
    oL0 = __builtin_amdgcn_mfma_f32_32x32x16_bf16(vf00, paL0, oL0, 0, 0, 0);
    oL1 = __builtin_amdgcn_mfma_f32_32x32x16_bf16(vf10, paL0, oL1, 0, 0, 0);
    oL0 = __builtin_amdgcn_mfma_f32_32x32x16_bf16(vf01, paL1, oL0, 0, 0, 0);
    oL1 = __builtin_amdgcn_mfma_f32_32x32x16_bf16(vf11, paL1, oL1, 0, 0, 0);
  }

  const int b = bh >> 4, h = bh & 15;
  store_o(oL0, oL1, lL, O + ((size_t)b * T_SEQ + q0L + l31) * C_DIM + h * DH, hi);
  store_o(oS0, oS1, lS, O + ((size_t)b * T_SEQ + q0S + l31) * C_DIM + h * DH, hi);
}

// ---------------------------------------------------------------------------
// Output projection, m97 structure with BK=64
// ---------------------------------------------------------------------------
__global__ __launch_bounds__(256) void msa_gemm_out(
    const bf16_t* __restrict__ ab, const bf16_t* __restrict__ wt,
    const float* __restrict__ bo, float* __restrict__ out) {
  __shared__ bf16_t lA[2 * 128 * 32];
  __shared__ bf16_t lB[2 * 128 * 32];
  const int tid = threadIdx.x;
  const int w = tid >> 6, lane = tid & 63;
  const int lr = lane & 15, lg = lane >> 4;
  const int m0 = blockIdx.y * 128;
  const int n0 = blockIdx.x * 128;
  const int wm = (w >> 1) * 64, wn = (w & 1) * 64;

  const int srow = tid >> 2, scol = (tid & 3) * 8;
  const bf16_t* ga = ab + (size_t)(m0 + srow) * C_DIM + scol;
  const bf16_t* gb = wt + (size_t)(n0 + srow) * C_DIM + scol;

  f32x4 acc[4][4];
#pragma unroll
  for (int i = 0; i < 4; i++)
#pragma unroll
    for (int j = 0; j < 4; j++) acc[i][j] = (f32x4){0.f, 0.f, 0.f, 0.f};

  for (int k0 = 0; k0 < C_DIM; k0 += 64) {
    gld_lds16(ga + k0, &lA[tid * 8]);
    gld_lds16(ga + (size_t)64 * C_DIM + k0, &lA[2048 + tid * 8]);
    gld_lds16(ga + k0 + 32, &lA[4096 + tid * 8]);
    gld_lds16(ga + (size_t)64 * C_DIM + k0 + 32, &lA[6144 + tid * 8]);
    gld_lds16(gb + k0, &lB[tid * 8]);
    gld_lds16(gb + (size_t)64 * C_DIM + k0, &lB[2048 + tid * 8]);
    gld_lds16(gb + k0 + 32, &lB[4096 + tid * 8]);
    gld_lds16(gb + (size_t)64 * C_DIM + k0 + 32, &lB[6144 + tid * 8]);
    __syncthreads();
#pragma unroll
    for (int h = 0; h < 2; h++) {
      bf16x8 a[4], b[4];
#pragma unroll
      for (int mb = 0; mb < 4; mb++)
        a[mb] = *(const bf16x8*)&lA[h * 4096 + (wm + mb * 16 + lr) * 32 + lg * 8];
#pragma unroll
      for (int nb = 0; nb < 4; nb++)
        b[nb] = *(const bf16x8*)&lB[h * 4096 + (wn + nb * 16 + lr) * 32 + lg * 8];
#pragma unroll
      for (int mb = 0; mb < 4; mb++)
#pragma unroll
        for (int nb = 0; nb < 4; nb++)
          acc[mb][nb] = __builtin_amdgcn_mfma_f32_16x16x32_bf16(a[mb], b[nb], acc[mb][nb], 0, 0, 0);
    }
    __syncthreads();
  }

#pragma unroll
  for (int nb = 0; nb < 4; nb++) {
    const int n = n0 + wn + nb * 16 + lr;
    const float bias = bo[n];
#pragma unroll
    for (int mb = 0; mb < 4; mb++) {
#pragma unroll
      for (int r = 0; r < 4; r++) {
        const int m = m0 + wm + mb * 16 + lg * 4 + r;
        out[(size_t)m * C_DIM + n] = acc[mb][nb][r] + bias;
      }
    }
  }
}

// ---------------------------------------------------------------------------
// launch
// ---------------------------------------------------------------------------
extern "C" void kernel_launch(void* const* d_in, const int* in_sizes, int n_in,
                              void* d_out, int out_size, void* d_ws, size_t ws_size,
                              hipStream_t stream) {
  const float* x  = (const float*)d_in[0];
  const float* wq = (const float*)d_in[2];
  const float* bq = (const float*)d_in[3];
  const float* wk = (const float*)d_in[4];
  const float* bk = (const float*)d_in[5];
  const float* wv = (const float*)d_in[6];
  const float* bv = (const float*)d_in[7];
  const float* wo = (const float*)d_in[8];
  const float* bo = (const float*)d_in[9];

  char* ws = (char*)d_ws;
  bf16_t* xb     = (bf16_t*)(ws);
  bf16_t* wt_qkv = (bf16_t*)(ws + (16ull << 20));
  bf16_t* wt_o   = (bf16_t*)(ws + (22ull << 20));
  bf16_t* qb     = (bf16_t*)(ws + (24ull << 20));
  bf16_t* kb     = (bf16_t*)(ws + (40ull << 20));
  bf16_t* vtb    = (bf16_t*)(ws + (56ull << 20));
  bf16_t* attn_o = xb;  // alias: xb dead after QKV GEMM

  const int n4 = M_TOK * C_DIM / 4;
  msa_cvt_x<<<n4 / 256, 256, 0, stream>>>(x, xb, n4);
  msa_transpose_w<<<dim3(32, 32, 4), 256, 0, stream>>>(wq, wk, wv, wo, wt_qkv, wt_o);
  msa_gemm_qkv<<<dim3(24, 64), 256, 0, stream>>>(xb, wt_qkv, bq, bk, bv, qb, kb, vtb);
  msa_attn32<<<dim3(64, 32), 64, 0, stream>>>(qb, kb, vtb, attn_o);
  msa_gemm_out<<<dim3(8, 64), 256, 0, stream>>>(attn_o, wt_o, bo, (float*)d_out);
}

// Round 10
// 191.003 us; speedup vs baseline: 1.3071x; 1.1843x over previous
//
#include <hip/hip_runtime.h>

typedef __bf16 bf16_t;
typedef bf16_t bf16x8 __attribute__((ext_vector_type(8)));
typedef bf16_t bf16x4 __attribute__((ext_vector_type(4)));
typedef float  f32x4  __attribute__((ext_vector_type(4)));
typedef float  f32x16 __attribute__((ext_vector_type(16)));
typedef unsigned int u32;
typedef u32 u32x2 __attribute__((ext_vector_type(2)));
typedef u32 u32x4 __attribute__((ext_vector_type(4)));

#define T_SEQ 2048
#define C_DIM 1024
#define NH    16
#define DH    64
#define BATCH 4
#define M_TOK (BATCH * T_SEQ)   // 8192

// Q pre-scale: 1/sqrt(64) * log2(e)  -> softmax computed in exp2 domain
#define Q_SCALE 0.1803368801111137f
#define DEFER_THR 8.0f

#define AS1 __attribute__((address_space(1)))
#define AS3 __attribute__((address_space(3)))

__device__ __forceinline__ void gld_lds16(const bf16_t* g, bf16_t* l) {
  __builtin_amdgcn_global_load_lds(
      (const AS1 u32*)(uintptr_t)g,
      (AS3 u32*)(u32)(uintptr_t)l, 16, 0, 0);
}

// v_permlane32_swap_b32: swaps a[32+i] <-> b[i].
__device__ __forceinline__ void plswap(u32& a, u32& b) {
  u32x2 r = __builtin_amdgcn_permlane32_swap(a, b, false, false);
  a = r[0]; b = r[1];
}
__device__ __forceinline__ float xmax32(float x) {
  u32 a = __builtin_bit_cast(u32, x), b = a;
  plswap(a, b);
  return fmaxf(__builtin_bit_cast(float, a), __builtin_bit_cast(float, b));
}
__device__ __forceinline__ float xsum32(float x) {
  u32 a = __builtin_bit_cast(u32, x), b = a;
  plswap(a, b);
  return __builtin_bit_cast(float, a) + __builtin_bit_cast(float, b);
}

// ---------------------------------------------------------------------------
// prep: x f32 -> bf16
// ---------------------------------------------------------------------------
__global__ __launch_bounds__(256) void msa_cvt_x(const float* __restrict__ x,
                                                 bf16_t* __restrict__ xb, int n4) {
  int i = blockIdx.x * 256 + threadIdx.x;
  if (i < n4) {
    const float4 v = ((const float4*)x)[i];
    bf16x4 o;
    o[0] = (bf16_t)v.x; o[1] = (bf16_t)v.y; o[2] = (bf16_t)v.z; o[3] = (bf16_t)v.w;
    ((bf16x4*)xb)[i] = o;
  }
}

// ---------------------------------------------------------------------------
// prep: weight transpose+convert: w[k][n] f32 -> wt[n][k] bf16
// ---------------------------------------------------------------------------
__global__ __launch_bounds__(256) void msa_transpose_w(
    const float* __restrict__ wq, const float* __restrict__ wk,
    const float* __restrict__ wv, const float* __restrict__ wo,
    bf16_t* __restrict__ wt_qkv, bf16_t* __restrict__ wt_o) {
  __shared__ float tile[32][33];
  const int a = blockIdx.z;
  const float* src = (a == 0) ? wq : (a == 1) ? wk : (a == 2) ? wv : wo;
  bf16_t* dst = (a < 3) ? (wt_qkv + (size_t)a * C_DIM * C_DIM) : wt_o;
  const int tx = threadIdx.x & 31, ty = threadIdx.x >> 5;
  const int bi = blockIdx.y * 32, bj = blockIdx.x * 32;
#pragma unroll
  for (int p = 0; p < 4; p++) {
    int r = p * 8 + ty;
    tile[r][tx] = src[(size_t)(bi + r) * C_DIM + bj + tx];
  }
  __syncthreads();
#pragma unroll
  for (int p = 0; p < 4; p++) {
    int r = p * 8 + ty;
    dst[(size_t)(bj + r) * C_DIM + bi + tx] = (bf16_t)tile[tx][r];
  }
}

// ---------------------------------------------------------------------------
// QKV GEMM, m97 structure with BK=64
// ---------------------------------------------------------------------------
__global__ __launch_bounds__(256) void msa_gemm_qkv(
    const bf16_t* __restrict__ xb, const bf16_t* __restrict__ wt,
    const float* __restrict__ bq, const float* __restrict__ bk,
    const float* __restrict__ bv,
    bf16_t* __restrict__ qo, bf16_t* __restrict__ ko, bf16_t* __restrict__ vto) {
  __shared__ bf16_t lA[2 * 128 * 32];
  __shared__ bf16_t lB[2 * 128 * 32];
  const int tid = threadIdx.x;
  const int w = tid >> 6, lane = tid & 63;
  const int lr = lane & 15, lg = lane >> 4;
  const int m0 = blockIdx.y * 128;
  const int n0 = blockIdx.x * 128;
  const int wm = (w >> 1) * 64, wn = (w & 1) * 64;

  const int srow = tid >> 2, scol = (tid & 3) * 8;
  const bf16_t* ga = xb + (size_t)(m0 + srow) * C_DIM + scol;
  const bf16_t* gb = wt + (size_t)(n0 + srow) * C_DIM + scol;

  f32x4 acc[4][4];
#pragma unroll
  for (int i = 0; i < 4; i++)
#pragma unroll
    for (int j = 0; j < 4; j++) acc[i][j] = (f32x4){0.f, 0.f, 0.f, 0.f};

  for (int k0 = 0; k0 < C_DIM; k0 += 64) {
    gld_lds16(ga + k0, &lA[tid * 8]);
    gld_lds16(ga + (size_t)64 * C_DIM + k0, &lA[2048 + tid * 8]);
    gld_lds16(ga + k0 + 32, &lA[4096 + tid * 8]);
    gld_lds16(ga + (size_t)64 * C_DIM + k0 + 32, &lA[6144 + tid * 8]);
    gld_lds16(gb + k0, &lB[tid * 8]);
    gld_lds16(gb + (size_t)64 * C_DIM + k0, &lB[2048 + tid * 8]);
    gld_lds16(gb + k0 + 32, &lB[4096 + tid * 8]);
    gld_lds16(gb + (size_t)64 * C_DIM + k0 + 32, &lB[6144 + tid * 8]);
    __syncthreads();
#pragma unroll
    for (int h = 0; h < 2; h++) {
      bf16x8 a[4], b[4];
#pragma unroll
      for (int mb = 0; mb < 4; mb++)
        a[mb] = *(const bf16x8*)&lA[h * 4096 + (wm + mb * 16 + lr) * 32 + lg * 8];
#pragma unroll
      for (int nb = 0; nb < 4; nb++)
        b[nb] = *(const bf16x8*)&lB[h * 4096 + (wn + nb * 16 + lr) * 32 + lg * 8];
#pragma unroll
      for (int mb = 0; mb < 4; mb++)
#pragma unroll
        for (int nb = 0; nb < 4; nb++)
          acc[mb][nb] = __builtin_amdgcn_mfma_f32_16x16x32_bf16(a[mb], b[nb], acc[mb][nb], 0, 0, 0);
    }
    __syncthreads();
  }

#pragma unroll
  for (int nb = 0; nb < 4; nb++) {
    const int n = n0 + wn + nb * 16 + lr;
    const int g = n >> 10, c = n & 1023, h = c >> 6, d = c & 63;
    const float bias = (g == 0) ? bq[c] : (g == 1) ? bk[c] : bv[c];
#pragma unroll
    for (int mb = 0; mb < 4; mb++) {
#pragma unroll
      for (int r = 0; r < 4; r++) {
        const int m = m0 + wm + mb * 16 + lg * 4 + r;
        const int bi = m >> 11, t = m & (T_SEQ - 1);
        float v = acc[mb][nb][r] + bias;
        if (g == 0)
          qo[(((size_t)bi * NH + h) * T_SEQ + t) * DH + d] = (bf16_t)(v * Q_SCALE);
        else if (g == 1)
          ko[(((size_t)bi * NH + h) * T_SEQ + t) * DH + d] = (bf16_t)v;
        else
          vto[(((size_t)bi * NH + h) * DH + d) * T_SEQ + t] = (bf16_t)v;
      }
    }
  }
}

// ---------------------------------------------------------------------------
// attn: softmax + pack helpers (permlane, no LDS) — unchanged from R8/R9
// ---------------------------------------------------------------------------
__device__ __forceinline__ void pack_frag(const f32x16& s, bf16x8& pa0, bf16x8& pa1) {
  u32 pk8[8];
#pragma unroll
  for (int i = 0; i < 8; i++) {
    const unsigned short lo = __builtin_bit_cast(unsigned short, (bf16_t)s[2 * i]);
    const unsigned short hh = __builtin_bit_cast(unsigned short, (bf16_t)s[2 * i + 1]);
    pk8[i] = ((u32)hh << 16) | (u32)lo;
  }
  u32 f0w0 = pk8[0], f0w2 = pk8[2];
  u32 f0w1 = pk8[1], f0w3 = pk8[3];
  u32 f1w0 = pk8[4], f1w2 = pk8[6];
  u32 f1w1 = pk8[5], f1w3 = pk8[7];
  plswap(f0w0, f0w2);
  plswap(f0w1, f0w3);
  plswap(f1w0, f1w2);
  plswap(f1w1, f1w3);
  const u32x4 q0v = {f0w0, f0w1, f0w2, f0w3};
  const u32x4 q1v = {f1w0, f1w1, f1w2, f1w3};
  pa0 = __builtin_bit_cast(bf16x8, q0v);
  pa1 = __builtin_bit_cast(bf16x8, q1v);
}

__device__ __forceinline__ void sm_pack(f32x16& s, float& m_run, float& l_run,
                                        f32x16& o0, f32x16& o1,
                                        bf16x8& pa0, bf16x8& pa1) {
  float t0 = fmaxf(fmaxf(s[0], s[1]), s[2]);
  float t1 = fmaxf(fmaxf(s[3], s[4]), s[5]);
  float t2 = fmaxf(fmaxf(s[6], s[7]), s[8]);
  float t3 = fmaxf(fmaxf(s[9], s[10]), s[11]);
  float t4 = fmaxf(fmaxf(s[12], s[13]), s[14]);
  float t5 = fmaxf(fmaxf(t0, t1), s[15]);
  float mt = fmaxf(fmaxf(fmaxf(t2, t3), t4), t5);
  mt = xmax32(mt);

  if (__any(mt > m_run + DEFER_THR)) {
    const float mnew = fmaxf(m_run, mt);
    const float al = __builtin_amdgcn_exp2f(m_run - mnew);
    m_run = mnew;
    l_run *= al;
#pragma unroll
    for (int r = 0; r < 16; r++) { o0[r] *= al; o1[r] *= al; }
  }

#pragma unroll
  for (int r = 0; r < 16; r++) s[r] = __builtin_amdgcn_exp2f(s[r] - m_run);
  {
    float a0 = (s[0] + s[1]) + (s[2] + s[3]);
    float a1 = (s[4] + s[5]) + (s[6] + s[7]);
    float a2 = (s[8] + s[9]) + (s[10] + s[11]);
    float a3 = (s[12] + s[13]) + (s[14] + s[15]);
    l_run += xsum32((a0 + a1) + (a2 + a3));
  }
  pack_frag(s, pa0, pa1);
}

__device__ __forceinline__ void store_o(f32x16& o0, f32x16& o1, float l_fin,
                                        bf16_t* __restrict__ orow, const int hi) {
  const float inv = 1.0f / l_fin;
#pragma unroll
  for (int db = 0; db < 2; db++) {
#pragma unroll
    for (int r = 0; r < 16; r += 2) {
      const int d = db * 32 + (r & 3) + 8 * (r >> 2) + 4 * hi;
      const float v0 = (db ? o1[r] : o0[r]) * inv;
      const float v1 = (db ? o1[r + 1] : o0[r + 1]) * inv;
      const unsigned short b0 = __builtin_bit_cast(unsigned short, (bf16_t)v0);
      const unsigned short b1 = __builtin_bit_cast(unsigned short, (bf16_t)v1);
      *reinterpret_cast<u32*>(orow + d) = ((u32)b1 << 16) | (u32)b0;
    }
  }
}

// ---------------------------------------------------------------------------
// Flash attention (causal): LDS-staged K/V shared across 4 waves.
// Grid (bh=64, pg=8), 256 threads. Wave w owns pair (tS=4pg+w, tL=63-4pg-w);
// block stages kt = 0..63-4pg (wave0's range) double-buffered via
// global_load_lds; waves with shorter ranges idle <=3 trailing slots.
// Swizzles (rule #21, source perm == read perm):
//   K tile [32 j][64 d] bf16: byte u -> u ^ ((row&7)<<4)  (conflict-free b128)
//   V tile [64 d][32 t] bf16: byte u -> u ^ ((row&3)<<4)  (floor-rate)
// Per-wave per-tile stream shrinks: 8 global loads + ~25 addr-VALU ->
// 8 ds_reads + ~8; staging amortized 4x. Dual-stream/defer-max/permlane
// softmax unchanged.
// ---------------------------------------------------------------------------
__global__ __launch_bounds__(256, 2) void msa_attn_lds(
    const bf16_t* __restrict__ Q, const bf16_t* __restrict__ K,
    const bf16_t* __restrict__ Vt, bf16_t* __restrict__ O) {
  __shared__ __align__(16) char lds[16384];  // [buf][K 4KB | V 4KB]
  const int tid = threadIdx.x;
  const int w = tid >> 6;
  const int lane = tid & 63;
  const int l31 = lane & 31;
  const int hi = lane >> 5;
  const int bh = blockIdx.x;
  const int pg = blockIdx.y;          // pg=0 (longest) dispatched first
  const int p = pg * 4 + w;
  const int tS = p, tL = 63 - p;
  const int q0S = tS * 32, q0L = tL * 32;
  const int KT_MAX = 63 - 4 * pg;

  const bf16_t* Qh = Q + (size_t)bh * T_SEQ * DH;
  const bf16_t* Kh = K + (size_t)bh * T_SEQ * DH;
  const bf16_t* Vh = Vt + (size_t)bh * DH * T_SEQ;

  bf16x8 qfL[4], qfS[4];
#pragma unroll
  for (int dc = 0; dc < 4; dc++) {
    qfL[dc] = *(const bf16x8*)(Qh + (size_t)(q0L + l31) * DH + dc * 16 + hi * 8);
    qfS[dc] = *(const bf16x8*)(Qh + (size_t)(q0S + l31) * DH + dc * 16 + hi * 8);
  }

  f32x16 oL0, oL1, oS0, oS1;
#pragma unroll
  for (int r = 0; r < 16; r++) { oL0[r] = 0.f; oL1[r] = 0.f; oS0[r] = 0.f; oS1[r] = 0.f; }
  float mL = -1e30f, lL = 0.f, mS = -1e30f, lS = 0.f;
  const f32x16 z16 = {};

  // read-side swizzle constants
  const int ksw = (l31 & 7) << 4;
  const int vsw = (l31 & 3) << 4;
  // stage-side (source) swizzled offsets
  const int krow = tid >> 3;                                 // 0..31
  const int kce = ((16 * (tid & 7)) ^ ((krow & 7) << 4)) >> 1;  // elem col
  const int vrow = tid >> 2;                                 // 0..63
  const int vce = ((16 * (tid & 3)) ^ ((vrow & 3) << 4)) >> 1;

#define STAGE(KT, BUF)                                                         \
  {                                                                            \
    const int jj = (KT) * 32;                                                  \
    bf16_t* base_ = (bf16_t*)(lds + (BUF) * 8192);                             \
    gld_lds16(Kh + (size_t)(jj + krow) * DH + kce, base_ + tid * 8);           \
    gld_lds16(Vh + (size_t)vrow * T_SEQ + jj + vce, base_ + 2048 + tid * 8);   \
  }

  STAGE(0, 0);
  __syncthreads();

  for (int kt = 0; kt <= KT_MAX; ++kt) {
    const int buf = kt & 1;
    if (kt < KT_MAX) STAGE(kt + 1, buf ^ 1);

    const bool doL = (kt <= tL);  // doS implies doL (tS < tL)
    if (doL) {
      const char* kb = lds + buf * 8192;
      const char* vb = kb + 4096;
      bf16x8 kf[4];
#pragma unroll
      for (int dc = 0; dc < 4; dc++)
        kf[dc] = *(const bf16x8*)(kb + l31 * 128 + ((dc * 32 + hi * 16) ^ ksw));
      const bf16x8 vf00 = *(const bf16x8*)(vb + l31 * 64 + ((hi * 16) ^ vsw));
      const bf16x8 vf01 = *(const bf16x8*)(vb + l31 * 64 + ((32 + hi * 16) ^ vsw));
      const bf16x8 vf10 = *(const bf16x8*)(vb + (32 + l31) * 64 + ((hi * 16) ^ vsw));
      const bf16x8 vf11 = *(const bf16x8*)(vb + (32 + l31) * 64 + ((32 + hi * 16) ^ vsw));

      const bool doS = (kt <= tS);
      f32x16 sL = __builtin_amdgcn_mfma_f32_32x32x16_bf16(kf[0], qfL[0], z16, 0, 0, 0);
#pragma unroll
      for (int dc = 1; dc < 4; dc++)
        sL = __builtin_amdgcn_mfma_f32_32x32x16_bf16(kf[dc], qfL[dc], sL, 0, 0, 0);
      f32x16 sS;
      if (doS) {
        sS = __builtin_amdgcn_mfma_f32_32x32x16_bf16(kf[0], qfS[0], z16, 0, 0, 0);
#pragma unroll
        for (int dc = 1; dc < 4; dc++)
          sS = __builtin_amdgcn_mfma_f32_32x32x16_bf16(kf[dc], qfS[dc], sS, 0, 0, 0);
      }
      if (kt == tL) {
#pragma unroll
        for (int r = 0; r < 16; r++) {
          const int jrow = (r & 3) + 8 * (r >> 2) + 4 * hi;
          if (jrow > l31) sL[r] = -1e30f;
        }
      }
      if (kt == tS) {
#pragma unroll
        for (int r = 0; r < 16; r++) {
          const int jrow = (r & 3) + 8 * (r >> 2) + 4 * hi;
          if (jrow > l31) sS[r] = -1e30f;
        }
      }
      bf16x8 paL0, paL1;
      sm_pack(sL, mL, lL, oL0, oL1, paL0, paL1);
      oL0 = __builtin_amdgcn_mfma_f32_32x32x16_bf16(vf00, paL0, oL0, 0, 0, 0);
      oL1 = __builtin_amdgcn_mfma_f32_32x32x16_bf16(vf10, paL0, oL1, 0, 0, 0);
      oL0 = __builtin_amdgcn_mfma_f32_32x32x16_bf16(vf01, paL1, oL0, 0, 0, 0);
      oL1 = __builtin_amdgcn_mfma_f32_32x32x16_bf16(vf11, paL1, oL1, 0, 0, 0);
      if (doS) {
        bf16x8 paS0, paS1;
        sm_pack(sS, mS, lS, oS0, oS1, paS0, paS1);
        oS0 = __builtin_amdgcn_mfma_f32_32x32x16_bf16(vf00, paS0, oS0, 0, 0, 0);
        oS1 = __builtin_amdgcn_mfma_f32_32x32x16_bf16(vf10, paS0, oS1, 0, 0, 0);
        oS0 = __builtin_amdgcn_mfma_f32_32x32x16_bf16(vf01, paS1, oS0, 0, 0, 0);
        oS1 = __builtin_amdgcn_mfma_f32_32x32x16_bf16(vf11, paS1, oS1, 0, 0, 0);
      }
    }
    __syncthreads();
  }
#undef STAGE

  const int b = bh >> 4, h = bh & 15;
  store_o(oL0, oL1, lL, O + ((size_t)b * T_SEQ + q0L + l31) * C_DIM + h * DH, hi);
  store_o(oS0, oS1, lS, O + ((size_t)b * T_SEQ + q0S + l31) * C_DIM + h * DH, hi);
}

// ---------------------------------------------------------------------------
// Output projection, m97 structure with BK=64
// ---------------------------------------------------------------------------
__global__ __launch_bounds__(256) void msa_gemm_out(
    const bf16_t* __restrict__ ab, const bf16_t* __restrict__ wt,
    const float* __restrict__ bo, float* __restrict__ out) {
  __shared__ bf16_t lA[2 * 128 * 32];
  __shared__ bf16_t lB[2 * 128 * 32];
  const int tid = threadIdx.x;
  const int w = tid >> 6, lane = tid & 63;
  const int lr = lane & 15, lg = lane >> 4;
  const int m0 = blockIdx.y * 128;
  const int n0 = blockIdx.x * 128;
  const int wm = (w >> 1) * 64, wn = (w & 1) * 64;

  const int srow = tid >> 2, scol = (tid & 3) * 8;
  const bf16_t* ga = ab + (size_t)(m0 + srow) * C_DIM + scol;
  const bf16_t* gb = wt + (size_t)(n0 + srow) * C_DIM + scol;

  f32x4 acc[4][4];
#pragma unroll
  for (int i = 0; i < 4; i++)
#pragma unroll
    for (int j = 0; j < 4; j++) acc[i][j] = (f32x4){0.f, 0.f, 0.f, 0.f};

  for (int k0 = 0; k0 < C_DIM; k0 += 64) {
    gld_lds16(ga + k0, &lA[tid * 8]);
    gld_lds16(ga + (size_t)64 * C_DIM + k0, &lA[2048 + tid * 8]);
    gld_lds16(ga + k0 + 32, &lA[4096 + tid * 8]);
    gld_lds16(ga + (size_t)64 * C_DIM + k0 + 32, &lA[6144 + tid * 8]);
    gld_lds16(gb + k0, &lB[tid * 8]);
    gld_lds16(gb + (size_t)64 * C_DIM + k0, &lB[2048 + tid * 8]);
    gld_lds16(gb + k0 + 32, &lB[4096 + tid * 8]);
    gld_lds16(gb + (size_t)64 * C_DIM + k0 + 32, &lB[6144 + tid * 8]);
    __syncthreads();
#pragma unroll
    for (int h = 0; h < 2; h++) {
      bf16x8 a[4], b[4];
#pragma unroll
      for (int mb = 0; mb < 4; mb++)
        a[mb] = *(const bf16x8*)&lA[h * 4096 + (wm + mb * 16 + lr) * 32 + lg * 8];
#pragma unroll
      for (int nb = 0; nb < 4; nb++)
        b[nb] = *(const bf16x8*)&lB[h * 4096 + (wn + nb * 16 + lr) * 32 + lg * 8];
#pragma unroll
      for (int mb = 0; mb < 4; mb++)
#pragma unroll
        for (int nb = 0; nb < 4; nb++)
          acc[mb][nb] = __builtin_amdgcn_mfma_f32_16x16x32_bf16(a[mb], b[nb], acc[mb][nb], 0, 0, 0);
    }
    __syncthreads();
  }

#pragma unroll
  for (int nb = 0; nb < 4; nb++) {
    const int n = n0 + wn + nb * 16 + lr;
    const float bias = bo[n];
#pragma unroll
    for (int mb = 0; mb < 4; mb++) {
#pragma unroll
      for (int r = 0; r < 4; r++) {
        const int m = m0 + wm + mb * 16 + lg * 4 + r;
        out[(size_t)m * C_DIM + n] = acc[mb][nb][r] + bias;
      }
    }
  }
}

// ---------------------------------------------------------------------------
// launch
// ---------------------------------------------------------------------------
extern "C" void kernel_launch(void* const* d_in, const int* in_sizes, int n_in,
                              void* d_out, int out_size, void* d_ws, size_t ws_size,
                              hipStream_t stream) {
  const float* x  = (const float*)d_in[0];
  const float* wq = (const float*)d_in[2];
  const float* bq = (const float*)d_in[3];
  const float* wk = (const float*)d_in[4];
  const float* bk = (const float*)d_in[5];
  const float* wv = (const float*)d_in[6];
  const float* bv = (const float*)d_in[7];
  const float* wo = (const float*)d_in[8];
  const float* bo = (const float*)d_in[9];

  char* ws = (char*)d_ws;
  bf16_t* xb     = (bf16_t*)(ws);
  bf16_t* wt_qkv = (bf16_t*)(ws + (16ull << 20));
  bf16_t* wt_o   = (bf16_t*)(ws + (22ull << 20));
  bf16_t* qb     = (bf16_t*)(ws + (24ull << 20));
  bf16_t* kb     = (bf16_t*)(ws + (40ull << 20));
  bf16_t* vtb    = (bf16_t*)(ws + (56ull << 20));
  bf16_t* attn_o = xb;  // alias: xb dead after QKV GEMM

  const int n4 = M_TOK * C_DIM / 4;
  msa_cvt_x<<<n4 / 256, 256, 0, stream>>>(x, xb, n4);
  msa_transpose_w<<<dim3(32, 32, 4), 256, 0, stream>>>(wq, wk, wv, wo, wt_qkv, wt_o);
  msa_gemm_qkv<<<dim3(24, 64), 256, 0, stream>>>(xb, wt_qkv, bq, bk, bv, qb, kb, vtb);
  msa_attn_lds<<<dim3(64, 8), 256, 0, stream>>>(qb, kb, vtb, attn_o);
  msa_gemm_out<<<dim3(8, 64), 256, 0, stream>>>(attn_o, wt_o, bo, (float*)d_out);
}

// Round 12
// 187.275 us; speedup vs baseline: 1.3331x; 1.0199x over previous
//
#include <hip/hip_runtime.h>

typedef __bf16 bf16_t;
typedef bf16_t bf16x8 __attribute__((ext_vector_type(8)));
typedef bf16_t bf16x4 __attribute__((ext_vector_type(4)));
typedef float  f32x4  __attribute__((ext_vector_type(4)));
typedef float  f32x16 __attribute__((ext_vector_type(16)));
typedef unsigned int u32;
typedef u32 u32x2 __attribute__((ext_vector_type(2)));
typedef u32 u32x4 __attribute__((ext_vector_type(4)));

#define T_SEQ 2048
#define C_DIM 1024
#define NH    16
#define DH    64
#define BATCH 4
#define M_TOK (BATCH * T_SEQ)   // 8192

// Q pre-scale: 1/sqrt(64) * log2(e)  -> softmax computed in exp2 domain
#define Q_SCALE 0.1803368801111137f
#define DEFER_THR 8.0f

#define AS1 __attribute__((address_space(1)))
#define AS3 __attribute__((address_space(3)))

__device__ __forceinline__ void gld_lds16(const bf16_t* g, bf16_t* l) {
  __builtin_amdgcn_global_load_lds(
      (const AS1 u32*)(uintptr_t)g,
      (AS3 u32*)(u32)(uintptr_t)l, 16, 0, 0);
}

// v_permlane32_swap_b32: swaps a[32+i] <-> b[i].
__device__ __forceinline__ void plswap(u32& a, u32& b) {
  u32x2 r = __builtin_amdgcn_permlane32_swap(a, b, false, false);
  a = r[0]; b = r[1];
}
__device__ __forceinline__ float xmax32(float x) {
  u32 a = __builtin_bit_cast(u32, x), b = a;
  plswap(a, b);
  return fmaxf(__builtin_bit_cast(float, a), __builtin_bit_cast(float, b));
}
__device__ __forceinline__ float xsum32(float x) {
  u32 a = __builtin_bit_cast(u32, x), b = a;
  plswap(a, b);
  return __builtin_bit_cast(float, a) + __builtin_bit_cast(float, b);
}

// ---------------------------------------------------------------------------
// prep: x f32 -> bf16
// ---------------------------------------------------------------------------
__global__ __launch_bounds__(256) void msa_cvt_x(const float* __restrict__ x,
                                                 bf16_t* __restrict__ xb, int n4) {
  int i = blockIdx.x * 256 + threadIdx.x;
  if (i < n4) {
    const float4 v = ((const float4*)x)[i];
    bf16x4 o;
    o[0] = (bf16_t)v.x; o[1] = (bf16_t)v.y; o[2] = (bf16_t)v.z; o[3] = (bf16_t)v.w;
    ((bf16x4*)xb)[i] = o;
  }
}

// ---------------------------------------------------------------------------
// prep: weight transpose+convert: w[k][n] f32 -> wt[n][k] bf16
// ---------------------------------------------------------------------------
__global__ __launch_bounds__(256) void msa_transpose_w(
    const float* __restrict__ wq, const float* __restrict__ wk,
    const float* __restrict__ wv, const float* __restrict__ wo,
    bf16_t* __restrict__ wt_qkv, bf16_t* __restrict__ wt_o) {
  __shared__ float tile[32][33];
  const int a = blockIdx.z;
  const float* src = (a == 0) ? wq : (a == 1) ? wk : (a == 2) ? wv : wo;
  bf16_t* dst = (a < 3) ? (wt_qkv + (size_t)a * C_DIM * C_DIM) : wt_o;
  const int tx = threadIdx.x & 31, ty = threadIdx.x >> 5;
  const int bi = blockIdx.y * 32, bj = blockIdx.x * 32;
#pragma unroll
  for (int p = 0; p < 4; p++) {
    int r = p * 8 + ty;
    tile[r][tx] = src[(size_t)(bi + r) * C_DIM + bj + tx];
  }
  __syncthreads();
#pragma unroll
  for (int p = 0; p < 4; p++) {
    int r = p * 8 + ty;
    dst[(size_t)(bj + r) * C_DIM + bi + tx] = (bf16_t)tile[tx][r];
  }
}

// ---------------------------------------------------------------------------
// GEMM core (T4+T2+T5 retrofit of m97 structure), R12: tail-vmcnt fixed.
// 128x128 tile, BK=32, 3-deep LDS rotation (48KB), counted vmcnt + raw
// s_barrier (prefetch loads stay in flight across barriers), XOR-swizzled
// LDS (both-sides), setprio around the MFMA cluster.
// Invariant: at end of iter kt, tile kt+1's loads must be retired. While
// staging is live (kt < NT-2) that is vmcnt(4); on the last two iterations
// it must be vmcnt(0) (no stage was issued -> 4 would be a no-op; this was
// the R11 race on the final K-tile).
// ---------------------------------------------------------------------------
#define GQ_BUF 16384

#define GEMM_CORE(APTR, BPTR, NT)                                              \
  __shared__ __align__(16) char lds[3 * GQ_BUF];                               \
  const int tid = threadIdx.x;                                                 \
  const int w = tid >> 6, lane = tid & 63;                                     \
  const int lr = lane & 15, lg = lane >> 4;                                    \
  const int m0 = blockIdx.y * 128;                                             \
  const int n0 = blockIdx.x * 128;                                             \
  const int wm = (w >> 1) * 64, wn = (w & 1) * 64;                             \
  const int rsw = (lg * 16) ^ ((lr & 3) << 4);                                 \
  int Aoff[4], Boff[4];                                                        \
  _Pragma("unroll") for (int f = 0; f < 4; f++) {                              \
    Aoff[f] = (wm + f * 16 + lr) * 64 + rsw;                                   \
    Boff[f] = 8192 + (wn + f * 16 + lr) * 64 + rsw;                            \
  }                                                                            \
  const int idx0 = tid, idx1 = 256 + tid;                                      \
  const int r0 = idx0 >> 2, c0 = ((idx0 & 3) ^ (r0 & 3)) * 8;                  \
  const int r1 = idx1 >> 2, c1 = ((idx1 & 3) ^ (r1 & 3)) * 8;                  \
  const bf16_t* gA0 = (APTR) + (size_t)(m0 + r0) * C_DIM + c0;                 \
  const bf16_t* gA1 = (APTR) + (size_t)(m0 + r1) * C_DIM + c1;                 \
  const bf16_t* gB0 = (BPTR) + (size_t)(n0 + r0) * C_DIM + c0;                 \
  const bf16_t* gB1 = (BPTR) + (size_t)(n0 + r1) * C_DIM + c1;                 \
  f32x4 acc[4][4];                                                             \
  _Pragma("unroll") for (int i = 0; i < 4; i++)                                \
    _Pragma("unroll") for (int j = 0; j < 4; j++)                              \
      acc[i][j] = (f32x4){0.f, 0.f, 0.f, 0.f};                                 \
  GSTG(0, 0);                                                                  \
  GSTG(1, GQ_BUF);                                                             \
  asm volatile("s_waitcnt vmcnt(4)" ::: "memory");                             \
  __builtin_amdgcn_s_barrier();                                                \
  __builtin_amdgcn_sched_barrier(0);                                           \
  int cb = 0;                                                                  \
  for (int kt = 0; kt < (NT); ++kt) {                                          \
    const char* base = lds + cb * GQ_BUF;                                      \
    bf16x8 a[4], b[4];                                                         \
    _Pragma("unroll") for (int f = 0; f < 4; f++) {                            \
      a[f] = *(const bf16x8*)(base + Aoff[f]);                                 \
      b[f] = *(const bf16x8*)(base + Boff[f]);                                 \
    }                                                                          \
    if (kt < (NT)-2) {                                                         \
      int sb = cb + 2; if (sb >= 3) sb -= 3;                                   \
      GSTG(kt + 2, sb * GQ_BUF);                                               \
    }                                                                          \
    __builtin_amdgcn_s_setprio(1);                                             \
    _Pragma("unroll") for (int mf = 0; mf < 4; mf++)                           \
      _Pragma("unroll") for (int nf = 0; nf < 4; nf++)                         \
        acc[mf][nf] = __builtin_amdgcn_mfma_f32_16x16x32_bf16(                 \
            a[mf], b[nf], acc[mf][nf], 0, 0, 0);                               \
    __builtin_amdgcn_s_setprio(0);                                             \
    if (kt < (NT)-2) {                                                         \
      asm volatile("s_waitcnt vmcnt(4)" ::: "memory");                         \
    } else {                                                                   \
      asm volatile("s_waitcnt vmcnt(0)" ::: "memory");                         \
    }                                                                          \
    __builtin_amdgcn_s_barrier();                                              \
    __builtin_amdgcn_sched_barrier(0);                                         \
    if (++cb == 3) cb = 0;                                                     \
  }

#define GSTG(KT, BB)                                                           \
  {                                                                            \
    bf16_t* d_ = (bf16_t*)(lds + (BB));                                        \
    gld_lds16(gA0 + (KT) * 32, d_ + tid * 8);                                  \
    gld_lds16(gA1 + (KT) * 32, d_ + 2048 + tid * 8);                           \
    gld_lds16(gB0 + (KT) * 32, d_ + 4096 + tid * 8);                           \
    gld_lds16(gB1 + (KT) * 32, d_ + 6144 + tid * 8);                           \
  }

// ---------------------------------------------------------------------------
// QKV GEMM -> Q (scaled), K, Vt
// ---------------------------------------------------------------------------
__global__ __launch_bounds__(256, 3) void msa_gemm_qkv(
    const bf16_t* __restrict__ xb, const bf16_t* __restrict__ wt,
    const float* __restrict__ bq, const float* __restrict__ bk,
    const float* __restrict__ bv,
    bf16_t* __restrict__ qo, bf16_t* __restrict__ ko, bf16_t* __restrict__ vto) {
  GEMM_CORE(xb, wt, 32)

#pragma unroll
  for (int nb = 0; nb < 4; nb++) {
    const int n = n0 + wn + nb * 16 + lr;
    const int g = n >> 10, c = n & 1023, h = c >> 6, d = c & 63;
    const float bias = (g == 0) ? bq[c] : (g == 1) ? bk[c] : bv[c];
#pragma unroll
    for (int mb = 0; mb < 4; mb++) {
#pragma unroll
      for (int r = 0; r < 4; r++) {
        const int m = m0 + wm + mb * 16 + lg * 4 + r;
        const int bi = m >> 11, t = m & (T_SEQ - 1);
        float v = acc[mb][nb][r] + bias;
        if (g == 0)
          qo[(((size_t)bi * NH + h) * T_SEQ + t) * DH + d] = (bf16_t)(v * Q_SCALE);
        else if (g == 1)
          ko[(((size_t)bi * NH + h) * T_SEQ + t) * DH + d] = (bf16_t)v;
        else
          vto[(((size_t)bi * NH + h) * DH + d) * T_SEQ + t] = (bf16_t)v;
      }
    }
  }
}

// ---------------------------------------------------------------------------
// Output projection
// ---------------------------------------------------------------------------
__global__ __launch_bounds__(256, 3) void msa_gemm_out(
    const bf16_t* __restrict__ ab, const bf16_t* __restrict__ wt,
    const float* __restrict__ bo, float* __restrict__ out) {
  GEMM_CORE(ab, wt, 32)

#pragma unroll
  for (int nb = 0; nb < 4; nb++) {
    const int n = n0 + wn + nb * 16 + lr;
    const float bias = bo[n];
#pragma unroll
    for (int mb = 0; mb < 4; mb++) {
#pragma unroll
      for (int r = 0; r < 4; r++) {
        const int m = m0 + wm + mb * 16 + lg * 4 + r;
        out[(size_t)m * C_DIM + n] = acc[mb][nb][r] + bias;
      }
    }
  }
}

// ---------------------------------------------------------------------------
// attn: softmax + pack helpers (permlane, no LDS)
// ---------------------------------------------------------------------------
__device__ __forceinline__ void pack_frag(const f32x16& s, bf16x8& pa0, bf16x8& pa1) {
  u32 pk8[8];
#pragma unroll
  for (int i = 0; i < 8; i++) {
    const unsigned short lo = __builtin_bit_cast(unsigned short, (bf16_t)s[2 * i]);
    const unsigned short hh = __builtin_bit_cast(unsigned short, (bf16_t)s[2 * i + 1]);
    pk8[i] = ((u32)hh << 16) | (u32)lo;
  }
  u32 f0w0 = pk8[0], f0w2 = pk8[2];
  u32 f0w1 = pk8[1], f0w3 = pk8[3];
  u32 f1w0 = pk8[4], f1w2 = pk8[6];
  u32 f1w1 = pk8[5], f1w3 = pk8[7];
  plswap(f0w0, f0w2);
  plswap(f0w1, f0w3);
  plswap(f1w0, f1w2);
  plswap(f1w1, f1w3);
  const u32x4 q0v = {f0w0, f0w1, f0w2, f0w3};
  const u32x4 q1v = {f1w0, f1w1, f1w2, f1w3};
  pa0 = __builtin_bit_cast(bf16x8, q0v);
  pa1 = __builtin_bit_cast(bf16x8, q1v);
}

__device__ __forceinline__ void sm_pack(f32x16& s, float& m_run, float& l_run,
                                        f32x16& o0, f32x16& o1,
                                        bf16x8& pa0, bf16x8& pa1) {
  float t0 = fmaxf(fmaxf(s[0], s[1]), s[2]);
  float t1 = fmaxf(fmaxf(s[3], s[4]), s[5]);
  float t2 = fmaxf(fmaxf(s[6], s[7]), s[8]);
  float t3 = fmaxf(fmaxf(s[9], s[10]), s[11]);
  float t4 = fmaxf(fmaxf(s[12], s[13]), s[14]);
  float t5 = fmaxf(fmaxf(t0, t1), s[15]);
  float mt = fmaxf(fmaxf(fmaxf(t2, t3), t4), t5);
  mt = xmax32(mt);

  if (__any(mt > m_run + DEFER_THR)) {
    const float mnew = fmaxf(m_run, mt);
    const float al = __builtin_amdgcn_exp2f(m_run - mnew);
    m_run = mnew;
    l_run *= al;
#pragma unroll
    for (int r = 0; r < 16; r++) { o0[r] *= al; o1[r] *= al; }
  }

#pragma unroll
  for (int r = 0; r < 16; r++) s[r] = __builtin_amdgcn_exp2f(s[r] - m_run);
  {
    float a0 = (s[0] + s[1]) + (s[2] + s[3]);
    float a1 = (s[4] + s[5]) + (s[6] + s[7]);
    float a2 = (s[8] + s[9]) + (s[10] + s[11]);
    float a3 = (s[12] + s[13]) + (s[14] + s[15]);
    l_run += xsum32((a0 + a1) + (a2 + a3));
  }
  pack_frag(s, pa0, pa1);
}

__device__ __forceinline__ void store_o(f32x16& o0, f32x16& o1, float l_fin,
                                        bf16_t* __restrict__ orow, const int hi) {
  const float inv = 1.0f / l_fin;
#pragma unroll
  for (int db = 0; db < 2; db++) {
#pragma unroll
    for (int r = 0; r < 16; r += 2) {
      const int d = db * 32 + (r & 3) + 8 * (r >> 2) + 4 * hi;
      const float v0 = (db ? o1[r] : o0[r]) * inv;
      const float v1 = (db ? o1[r + 1] : o0[r + 1]) * inv;
      const unsigned short b0 = __builtin_bit_cast(unsigned short, (bf16_t)v0);
      const unsigned short b1 = __builtin_bit_cast(unsigned short, (bf16_t)v1);
      *reinterpret_cast<u32*>(orow + d) = ((u32)b1 << 16) | (u32)b0;
    }
  }
}

// ---------------------------------------------------------------------------
// Flash attention (causal): LDS-staged K/V shared across 4 waves (R10, kept).
// ---------------------------------------------------------------------------
__global__ __launch_bounds__(256, 2) void msa_attn_lds(
    const bf16_t* __restrict__ Q, const bf16_t* __restrict__ K,
    const bf16_t* __restrict__ Vt, bf16_t* __restrict__ O) {
  __shared__ __align__(16) char lds[16384];  // [buf][K 4KB | V 4KB]
  const int tid = threadIdx.x;
  const int w = tid >> 6;
  const int lane = tid & 63;
  const int l31 = lane & 31;
  const int hi = lane >> 5;
  const int bh = blockIdx.x;
  const int pg = blockIdx.y;          // pg=0 (longest) dispatched first
  const int p = pg * 4 + w;
  const int tS = p, tL = 63 - p;
  const int q0S = tS * 32, q0L = tL * 32;
  const int KT_MAX = 63 - 4 * pg;

  const bf16_t* Qh = Q + (size_t)bh * T_SEQ * DH;
  const bf16_t* Kh = K + (size_t)bh * T_SEQ * DH;
  const bf16_t* Vh = Vt + (size_t)bh * DH * T_SEQ;

  bf16x8 qfL[4], qfS[4];
#pragma unroll
  for (int dc = 0; dc < 4; dc++) {
    qfL[dc] = *(const bf16x8*)(Qh + (size_t)(q0L + l31) * DH + dc * 16 + hi * 8);
    qfS[dc] = *(const bf16x8*)(Qh + (size_t)(q0S + l31) * DH + dc * 16 + hi * 8);
  }

  f32x16 oL0, oL1, oS0, oS1;
#pragma unroll
  for (int r = 0; r < 16; r++) { oL0[r] = 0.f; oL1[r] = 0.f; oS0[r] = 0.f; oS1[r] = 0.f; }
  float mL = -1e30f, lL = 0.f, mS = -1e30f, lS = 0.f;
  const f32x16 z16 = {};

  const int ksw = (l31 & 7) << 4;
  const int vsw = (l31 & 3) << 4;
  const int krow = tid >> 3;
  const int kce = ((16 * (tid & 7)) ^ ((krow & 7) << 4)) >> 1;
  const int vrow = tid >> 2;
  const int vce = ((16 * (tid & 3)) ^ ((vrow & 3) << 4)) >> 1;

#define STAGE(KT, BUF)                                                         \
  {                                                                            \
    const int jj = (KT) * 32;                                                  \
    bf16_t* base_ = (bf16_t*)(lds + (BUF) * 8192);                             \
    gld_lds16(Kh + (size_t)(jj + krow) * DH + kce, base_ + tid * 8);           \
    gld_lds16(Vh + (size_t)vrow * T_SEQ + jj + vce, base_ + 2048 + tid * 8);   \
  }

  STAGE(0, 0);
  __syncthreads();

  for (int kt = 0; kt <= KT_MAX; ++kt) {
    const int buf = kt & 1;
    if (kt < KT_MAX) STAGE(kt + 1, buf ^ 1);

    const bool doL = (kt <= tL);
    if (doL) {
      const char* kb = lds + buf * 8192;
      const char* vb = kb + 4096;
      bf16x8 kf[4];
#pragma unroll
      for (int dc = 0; dc < 4; dc++)
        kf[dc] = *(const bf16x8*)(kb + l31 * 128 + ((dc * 32 + hi * 16) ^ ksw));
      const bf16x8 vf00 = *(const bf16x8*)(vb + l31 * 64 + ((hi * 16) ^ vsw));
      const bf16x8 vf01 = *(const bf16x8*)(vb + l31 * 64 + ((32 + hi * 16) ^ vsw));
      const bf16x8 vf10 = *(const bf16x8*)(vb + (32 + l31) * 64 + ((hi * 16) ^ vsw));
      const bf16x8 vf11 = *(const bf16x8*)(vb + (32 + l31) * 64 + ((32 + hi * 16) ^ vsw));

      const bool doS = (kt <= tS);
      f32x16 sL = __builtin_amdgcn_mfma_f32_32x32x16_bf16(kf[0], qfL[0], z16, 0, 0, 0);
#pragma unroll
      for (int dc = 1; dc < 4; dc++)
        sL = __builtin_amdgcn_mfma_f32_32x32x16_bf16(kf[dc], qfL[dc], sL, 0, 0, 0);
      f32x16 sS;
      if (doS) {
        sS = __builtin_amdgcn_mfma_f32_32x32x16_bf16(kf[0], qfS[0], z16, 0, 0, 0);
#pragma unroll
        for (int dc = 1; dc < 4; dc++)
          sS = __builtin_amdgcn_mfma_f32_32x32x16_bf16(kf[dc], qfS[dc], sS, 0, 0, 0);
      }
      if (kt == tL) {
#pragma unroll
        for (int r = 0; r < 16; r++) {
          const int jrow = (r & 3) + 8 * (r >> 2) + 4 * hi;
          if (jrow > l31) sL[r] = -1e30f;
        }
      }
      if (kt == tS) {
#pragma unroll
        for (int r = 0; r < 16; r++) {
          const int jrow = (r & 3) + 8 * (r >> 2) + 4 * hi;
          if (jrow > l31) sS[r] = -1e30f;
        }
      }
      bf16x8 paL0, paL1;
      sm_pack(sL, mL, lL, oL0, oL1, paL0, paL1);
      oL0 = __builtin_amdgcn_mfma_f32_32x32x16_bf16(vf00, paL0, oL0, 0, 0, 0);
      oL1 = __builtin_amdgcn_mfma_f32_32x32x16_bf16(vf10, paL0, oL1, 0, 0, 0);
      oL0 = __builtin_amdgcn_mfma_f32_32x32x16_bf16(vf01, paL1, oL0, 0, 0, 0);
      oL1 = __builtin_amdgcn_mfma_f32_32x32x16_bf16(vf11, paL1, oL1, 0, 0, 0);
      if (doS) {
        bf16x8 paS0, paS1;
        sm_pack(sS, mS, lS, oS0, oS1, paS0, paS1);
        oS0 = __builtin_amdgcn_mfma_f32_32x32x16_bf16(vf00, paS0, oS0, 0, 0, 0);
        oS1 = __builtin_amdgcn_mfma_f32_32x32x16_bf16(vf10, paS0, oS1, 0, 0, 0);
        oS0 = __builtin_amdgcn_mfma_f32_32x32x16_bf16(vf01, paS1, oS0, 0, 0, 0);
        oS1 = __builtin_amdgcn_mfma_f32_32x32x16_bf16(vf11, paS1, oS1, 0, 0, 0);
      }
    }
    __syncthreads();
  }
#undef STAGE

  const int b = bh >> 4, h = bh & 15;
  store_o(oL0, oL1, lL, O + ((size_t)b * T_SEQ + q0L + l31) * C_DIM + h * DH, hi);
  store_o(oS0, oS1, lS, O + ((size_t)b * T_SEQ + q0S + l31) * C_DIM + h * DH, hi);
}

// ---------------------------------------------------------------------------
// launch
// ---------------------------------------------------------------------------
extern "C" void kernel_launch(void* const* d_in, const int* in_sizes, int n_in,
                              void* d_out, int out_size, void* d_ws, size_t ws_size,
                              hipStream_t stream) {
  const float* x  = (const float*)d_in[0];
  const float* wq = (const float*)d_in[2];
  const float* bq = (const float*)d_in[3];
  const float* wk = (const float*)d_in[4];
  const float* bk = (const float*)d_in[5];
  const float* wv = (const float*)d_in[6];
  const float* bv = (const float*)d_in[7];
  const float* wo = (const float*)d_in[8];
  const float* bo = (const float*)d_in[9];

  char* ws = (char*)d_ws;
  bf16_t* xb     = (bf16_t*)(ws);
  bf16_t* wt_qkv = (bf16_t*)(ws + (16ull << 20));
  bf16_t* wt_o   = (bf16_t*)(ws + (22ull << 20));
  bf16_t* qb     = (bf16_t*)(ws + (24ull << 20));
  bf16_t* kb     = (bf16_t*)(ws + (40ull << 20));
  bf16_t* vtb    = (bf16_t*)(ws + (56ull << 20));
  bf16_t* attn_o = xb;  // alias: xb dead after QKV GEMM

  const int n4 = M_TOK * C_DIM / 4;
  msa_cvt_x<<<n4 / 256, 256, 0, stream>>>(x, xb, n4);
  msa_transpose_w<<<dim3(32, 32, 4), 256, 0, stream>>>(wq, wk, wv, wo, wt_qkv, wt_o);
  msa_gemm_qkv<<<dim3(24, 64), 256, 0, stream>>>(xb, wt_qkv, bq, bk, bv, qb, kb, vtb);
  msa_attn_lds<<<dim3(64, 8), 256, 0, stream>>>(qb, kb, vtb, attn_o);
  msa_gemm_out<<<dim3(8, 64), 256, 0, stream>>>(attn_o, wt_o, bo, (float*)d_out);
}

// Round 13
// 169.410 us; speedup vs baseline: 1.4737x; 1.1055x over previous
//
#include <hip/hip_runtime.h>

typedef __bf16 bf16_t;
typedef bf16_t bf16x8 __attribute__((ext_vector_type(8)));
typedef bf16_t bf16x4 __attribute__((ext_vector_type(4)));
typedef float  f32x4  __attribute__((ext_vector_type(4)));
typedef float  f32x16 __attribute__((ext_vector_type(16)));
typedef unsigned int u32;
typedef u32 u32x2 __attribute__((ext_vector_type(2)));
typedef u32 u32x4 __attribute__((ext_vector_type(4)));

#define T_SEQ 2048
#define C_DIM 1024
#define NH    16
#define DH    64
#define BATCH 4
#define M_TOK (BATCH * T_SEQ)   // 8192

// Q pre-scale: 1/sqrt(64) * log2(e)  -> softmax computed in exp2 domain
#define Q_SCALE 0.1803368801111137f
#define DEFER_THR 8.0f

#define AS1 __attribute__((address_space(1)))
#define AS3 __attribute__((address_space(3)))

__device__ __forceinline__ void gld_lds16(const bf16_t* g, bf16_t* l) {
  __builtin_amdgcn_global_load_lds(
      (const AS1 u32*)(uintptr_t)g,
      (AS3 u32*)(u32)(uintptr_t)l, 16, 0, 0);
}

// v_permlane32_swap_b32: swaps a[32+i] <-> b[i].
__device__ __forceinline__ void plswap(u32& a, u32& b) {
  u32x2 r = __builtin_amdgcn_permlane32_swap(a, b, false, false);
  a = r[0]; b = r[1];
}
__device__ __forceinline__ float xmax32(float x) {
  u32 a = __builtin_bit_cast(u32, x), b = a;
  plswap(a, b);
  return fmaxf(__builtin_bit_cast(float, a), __builtin_bit_cast(float, b));
}
__device__ __forceinline__ float xsum32(float x) {
  u32 a = __builtin_bit_cast(u32, x), b = a;
  plswap(a, b);
  return __builtin_bit_cast(float, a) + __builtin_bit_cast(float, b);
}

__device__ __forceinline__ u32 pack_bf16_pair(float v0, float v1) {
  const unsigned short b0 = __builtin_bit_cast(unsigned short, (bf16_t)v0);
  const unsigned short b1 = __builtin_bit_cast(unsigned short, (bf16_t)v1);
  return ((u32)b1 << 16) | (u32)b0;
}

// ---------------------------------------------------------------------------
// prep: x f32 -> bf16
// ---------------------------------------------------------------------------
__global__ __launch_bounds__(256) void msa_cvt_x(const float* __restrict__ x,
                                                 bf16_t* __restrict__ xb, int n4) {
  int i = blockIdx.x * 256 + threadIdx.x;
  if (i < n4) {
    const float4 v = ((const float4*)x)[i];
    bf16x4 o;
    o[0] = (bf16_t)v.x; o[1] = (bf16_t)v.y; o[2] = (bf16_t)v.z; o[3] = (bf16_t)v.w;
    ((bf16x4*)xb)[i] = o;
  }
}

// ---------------------------------------------------------------------------
// prep: weight transpose+convert: w[k][n] f32 -> wt[n][k] bf16
// ---------------------------------------------------------------------------
__global__ __launch_bounds__(256) void msa_transpose_w(
    const float* __restrict__ wq, const float* __restrict__ wk,
    const float* __restrict__ wv, const float* __restrict__ wo,
    bf16_t* __restrict__ wt_qkv, bf16_t* __restrict__ wt_o) {
  __shared__ float tile[32][33];
  const int a = blockIdx.z;
  const float* src = (a == 0) ? wq : (a == 1) ? wk : (a == 2) ? wv : wo;
  bf16_t* dst = (a < 3) ? (wt_qkv + (size_t)a * C_DIM * C_DIM) : wt_o;
  const int tx = threadIdx.x & 31, ty = threadIdx.x >> 5;
  const int bi = blockIdx.y * 32, bj = blockIdx.x * 32;
#pragma unroll
  for (int p = 0; p < 4; p++) {
    int r = p * 8 + ty;
    tile[r][tx] = src[(size_t)(bi + r) * C_DIM + bj + tx];
  }
  __syncthreads();
#pragma unroll
  for (int p = 0; p < 4; p++) {
    int r = p * 8 + ty;
    dst[(size_t)(bj + r) * C_DIM + bi + tx] = (bf16_t)tile[tx][r];
  }
}

// ---------------------------------------------------------------------------
// GEMM core (R12-verified) + T1 XCD-contiguous block swizzle.
// 128x128 tile, BK=32, 3-deep LDS rotation (48KB), counted vmcnt(4) in-loop
// with vmcnt(0) on the final two iterations (tail invariant), balanced LDS
// layout, setprio around the MFMA cluster.
// ---------------------------------------------------------------------------
#define GQ_BUF 16384

#define GEMM_CORE(APTR, BPTR, NT)                                              \
  __shared__ __align__(16) char lds[3 * GQ_BUF];                               \
  const int tid = threadIdx.x;                                                 \
  const int w = tid >> 6, lane = tid & 63;                                     \
  const int lr = lane & 15, lg = lane >> 4;                                    \
  int bx_, by_;                                                                \
  {                                                                            \
    const int gx = gridDim.x;                                                  \
    const int nwg = gx * gridDim.y;                                            \
    int lin = blockIdx.y * gx + blockIdx.x;                                    \
    lin = (lin & 7) * (nwg >> 3) + (lin >> 3);                                 \
    bx_ = lin % gx; by_ = lin / gx;                                            \
  }                                                                            \
  const int m0 = by_ * 128;                                                    \
  const int n0 = bx_ * 128;                                                    \
  const int wm = (w >> 1) * 64, wn = (w & 1) * 64;                             \
  const int rsw = (lg * 16) ^ ((lr & 3) << 4);                                 \
  int Aoff[4], Boff[4];                                                        \
  _Pragma("unroll") for (int f = 0; f < 4; f++) {                              \
    Aoff[f] = (wm + f * 16 + lr) * 64 + rsw;                                   \
    Boff[f] = 8192 + (wn + f * 16 + lr) * 64 + rsw;                            \
  }                                                                            \
  const int idx0 = tid, idx1 = 256 + tid;                                      \
  const int r0 = idx0 >> 2, c0_ = ((idx0 & 3) ^ (r0 & 3)) * 8;                 \
  const int r1 = idx1 >> 2, c1_ = ((idx1 & 3) ^ (r1 & 3)) * 8;                 \
  const bf16_t* gA0 = (APTR) + (size_t)(m0 + r0) * C_DIM + c0_;                \
  const bf16_t* gA1 = (APTR) + (size_t)(m0 + r1) * C_DIM + c1_;                \
  const bf16_t* gB0 = (BPTR) + (size_t)(n0 + r0) * C_DIM + c0_;                \
  const bf16_t* gB1 = (BPTR) + (size_t)(n0 + r1) * C_DIM + c1_;                \
  f32x4 acc[4][4];                                                             \
  _Pragma("unroll") for (int i = 0; i < 4; i++)                                \
    _Pragma("unroll") for (int j = 0; j < 4; j++)                              \
      acc[i][j] = (f32x4){0.f, 0.f, 0.f, 0.f};                                 \
  GSTG(0, 0);                                                                  \
  GSTG(1, GQ_BUF);                                                             \
  asm volatile("s_waitcnt vmcnt(4)" ::: "memory");                             \
  __builtin_amdgcn_s_barrier();                                                \
  __builtin_amdgcn_sched_barrier(0);                                           \
  int cb = 0;                                                                  \
  for (int kt = 0; kt < (NT); ++kt) {                                          \
    const char* base = lds + cb * GQ_BUF;                                      \
    bf16x8 a[4], b[4];                                                         \
    _Pragma("unroll") for (int f = 0; f < 4; f++) {                            \
      a[f] = *(const bf16x8*)(base + Aoff[f]);                                 \
      b[f] = *(const bf16x8*)(base + Boff[f]);                                 \
    }                                                                          \
    if (kt < (NT)-2) {                                                         \
      int sb = cb + 2; if (sb >= 3) sb -= 3;                                   \
      GSTG(kt + 2, sb * GQ_BUF);                                               \
    }                                                                          \
    __builtin_amdgcn_s_setprio(1);                                             \
    _Pragma("unroll") for (int mf = 0; mf < 4; mf++)                           \
      _Pragma("unroll") for (int nf = 0; nf < 4; nf++)                         \
        acc[mf][nf] = __builtin_amdgcn_mfma_f32_16x16x32_bf16(                 \
            a[mf], b[nf], acc[mf][nf], 0, 0, 0);                               \
    __builtin_amdgcn_s_setprio(0);                                             \
    if (kt < (NT)-2) {                                                         \
      asm volatile("s_waitcnt vmcnt(4)" ::: "memory");                         \
    } else {                                                                   \
      asm volatile("s_waitcnt vmcnt(0)" ::: "memory");                         \
    }                                                                          \
    __builtin_amdgcn_s_barrier();                                              \
    __builtin_amdgcn_sched_barrier(0);                                         \
    if (++cb == 3) cb = 0;                                                     \
  }

#define GSTG(KT, BB)                                                           \
  {                                                                            \
    bf16_t* d_ = (bf16_t*)(lds + (BB));                                        \
    gld_lds16(gA0 + (KT) * 32, d_ + tid * 8);                                  \
    gld_lds16(gA1 + (KT) * 32, d_ + 2048 + tid * 8);                           \
    gld_lds16(gB0 + (KT) * 32, d_ + 4096 + tid * 8);                           \
    gld_lds16(gB1 + (KT) * 32, d_ + 6144 + tid * 8);                           \
  }

// ---------------------------------------------------------------------------
// QKV GEMM -> Q (scaled), K, Vt.  Every 128-col block is pure Q, K, or V
// (N=3072 splits on block boundaries).  V-blocks: thread's r=0..3 are 4
// consecutive t in Vt's [d][t] layout -> pack into one aligned 8B store
// (was 4 scattered 2B stores; WRITE_SIZE was +40% over ideal).
// ---------------------------------------------------------------------------
__global__ __launch_bounds__(256, 3) void msa_gemm_qkv(
    const bf16_t* __restrict__ xb, const bf16_t* __restrict__ wt,
    const float* __restrict__ bq, const float* __restrict__ bk,
    const float* __restrict__ bv,
    bf16_t* __restrict__ qo, bf16_t* __restrict__ ko, bf16_t* __restrict__ vto) {
  GEMM_CORE(xb, wt, 32)

  const int g = n0 >> 10;  // uniform per block
  if (g == 2) {
    // --- V: packed 8B scatter ---
#pragma unroll
    for (int nb = 0; nb < 4; nb++) {
      const int c = ((n0 + wn) & 1023) + nb * 16 + lr;
      const int h = c >> 6, d = c & 63;
      const float bias = bv[c];
      bf16_t* vrow = vto + (((size_t)((m0 >> 11) * NH + h)) * DH + d) * T_SEQ;
#pragma unroll
      for (int mb = 0; mb < 4; mb++) {
        const int t = (m0 & 2047) + wm + mb * 16 + lg * 4;
        u32x2 pr;
        pr[0] = pack_bf16_pair(acc[mb][nb][0] + bias, acc[mb][nb][1] + bias);
        pr[1] = pack_bf16_pair(acc[mb][nb][2] + bias, acc[mb][nb][3] + bias);
        *reinterpret_cast<u32x2*>(vrow + t) = pr;
      }
    }
  } else {
#pragma unroll
    for (int nb = 0; nb < 4; nb++) {
      const int n = n0 + wn + nb * 16 + lr;
      const int c = n & 1023, h = c >> 6, d = c & 63;
      const float bias = (g == 0) ? bq[c] : bk[c];
#pragma unroll
      for (int mb = 0; mb < 4; mb++) {
#pragma unroll
        for (int r = 0; r < 4; r++) {
          const int m = m0 + wm + mb * 16 + lg * 4 + r;
          const int bi = m >> 11, t = m & (T_SEQ - 1);
          float v = acc[mb][nb][r] + bias;
          if (g == 0)
            qo[(((size_t)bi * NH + h) * T_SEQ + t) * DH + d] = (bf16_t)(v * Q_SCALE);
          else
            ko[(((size_t)bi * NH + h) * T_SEQ + t) * DH + d] = (bf16_t)v;
        }
      }
    }
  }
}

// ---------------------------------------------------------------------------
// Output projection
// ---------------------------------------------------------------------------
__global__ __launch_bounds__(256, 3) void msa_gemm_out(
    const bf16_t* __restrict__ ab, const bf16_t* __restrict__ wt,
    const float* __restrict__ bo, float* __restrict__ out) {
  GEMM_CORE(ab, wt, 32)

#pragma unroll
  for (int nb = 0; nb < 4; nb++) {
    const int n = n0 + wn + nb * 16 + lr;
    const float bias = bo[n];
#pragma unroll
    for (int mb = 0; mb < 4; mb++) {
#pragma unroll
      for (int r = 0; r < 4; r++) {
        const int m = m0 + wm + mb * 16 + lg * 4 + r;
        out[(size_t)m * C_DIM + n] = acc[mb][nb][r] + bias;
      }
    }
  }
}

// ---------------------------------------------------------------------------
// attn: softmax + pack helpers (permlane, no LDS)
// ---------------------------------------------------------------------------
__device__ __forceinline__ void pack_frag(const f32x16& s, bf16x8& pa0, bf16x8& pa1) {
  u32 pk8[8];
#pragma unroll
  for (int i = 0; i < 8; i++) pk8[i] = pack_bf16_pair(s[2 * i], s[2 * i + 1]);
  u32 f0w0 = pk8[0], f0w2 = pk8[2];
  u32 f0w1 = pk8[1], f0w3 = pk8[3];
  u32 f1w0 = pk8[4], f1w2 = pk8[6];
  u32 f1w1 = pk8[5], f1w3 = pk8[7];
  plswap(f0w0, f0w2);
  plswap(f0w1, f0w3);
  plswap(f1w0, f1w2);
  plswap(f1w1, f1w3);
  const u32x4 q0v = {f0w0, f0w1, f0w2, f0w3};
  const u32x4 q1v = {f1w0, f1w1, f1w2, f1w3};
  pa0 = __builtin_bit_cast(bf16x8, q0v);
  pa1 = __builtin_bit_cast(bf16x8, q1v);
}

__device__ __forceinline__ void sm_pack(f32x16& s, float& m_run, float& l_run,
                                        f32x16& o0, f32x16& o1,
                                        bf16x8& pa0, bf16x8& pa1) {
  float t0 = fmaxf(fmaxf(s[0], s[1]), s[2]);
  float t1 = fmaxf(fmaxf(s[3], s[4]), s[5]);
  float t2 = fmaxf(fmaxf(s[6], s[7]), s[8]);
  float t3 = fmaxf(fmaxf(s[9], s[10]), s[11]);
  float t4 = fmaxf(fmaxf(s[12], s[13]), s[14]);
  float t5 = fmaxf(fmaxf(t0, t1), s[15]);
  float mt = fmaxf(fmaxf(fmaxf(t2, t3), t4), t5);
  mt = xmax32(mt);

  if (__any(mt > m_run + DEFER_THR)) {
    const float mnew = fmaxf(m_run, mt);
    const float al = __builtin_amdgcn_exp2f(m_run - mnew);
    m_run = mnew;
    l_run *= al;
#pragma unroll
    for (int r = 0; r < 16; r++) { o0[r] *= al; o1[r] *= al; }
  }

#pragma unroll
  for (int r = 0; r < 16; r++) s[r] = __builtin_amdgcn_exp2f(s[r] - m_run);
  {
    float a0 = (s[0] + s[1]) + (s[2] + s[3]);
    float a1 = (s[4] + s[5]) + (s[6] + s[7]);
    float a2 = (s[8] + s[9]) + (s[10] + s[11]);
    float a3 = (s[12] + s[13]) + (s[14] + s[15]);
    l_run += xsum32((a0 + a1) + (a2 + a3));
  }
  pack_frag(s, pa0, pa1);
}

__device__ __forceinline__ void store_o(f32x16& o0, f32x16& o1, float l_fin,
                                        bf16_t* __restrict__ orow, const int hi) {
  const float inv = 1.0f / l_fin;
#pragma unroll
  for (int db = 0; db < 2; db++) {
#pragma unroll
    for (int r = 0; r < 16; r += 2) {
      const int d = db * 32 + (r & 3) + 8 * (r >> 2) + 4 * hi;
      const float v0 = (db ? o1[r] : o0[r]) * inv;
      const float v1 = (db ? o1[r + 1] : o0[r + 1]) * inv;
      *reinterpret_cast<u32*>(orow + d) = pack_bf16_pair(v0, v1);
    }
  }
}

// ---------------------------------------------------------------------------
// Flash attention (causal): LDS-staged K/V shared across 4 waves (R10, kept).
// ---------------------------------------------------------------------------
__global__ __launch_bounds__(256, 2) void msa_attn_lds(
    const bf16_t* __restrict__ Q, const bf16_t* __restrict__ K,
    const bf16_t* __restrict__ Vt, bf16_t* __restrict__ O) {
  __shared__ __align__(16) char lds[16384];  // [buf][K 4KB | V 4KB]
  const int tid = threadIdx.x;
  const int w = tid >> 6;
  const int lane = tid & 63;
  const int l31 = lane & 31;
  const int hi = lane >> 5;
  const int bh = blockIdx.x;
  const int pg = blockIdx.y;          // pg=0 (longest) dispatched first
  const int p = pg * 4 + w;
  const int tS = p, tL = 63 - p;
  const int q0S = tS * 32, q0L = tL * 32;
  const int KT_MAX = 63 - 4 * pg;

  const bf16_t* Qh = Q + (size_t)bh * T_SEQ * DH;
  const bf16_t* Kh = K + (size_t)bh * T_SEQ * DH;
  const bf16_t* Vh = Vt + (size_t)bh * DH * T_SEQ;

  bf16x8 qfL[4], qfS[4];
#pragma unroll
  for (int dc = 0; dc < 4; dc++) {
    qfL[dc] = *(const bf16x8*)(Qh + (size_t)(q0L + l31) * DH + dc * 16 + hi * 8);
    qfS[dc] = *(const bf16x8*)(Qh + (size_t)(q0S + l31) * DH + dc * 16 + hi * 8);
  }

  f32x16 oL0, oL1, oS0, oS1;
#pragma unroll
  for (int r = 0; r < 16; r++) { oL0[r] = 0.f; oL1[r] = 0.f; oS0[r] = 0.f; oS1[r] = 0.f; }
  float mL = -1e30f, lL = 0.f, mS = -1e30f, lS = 0.f;
  const f32x16 z16 = {};

  const int ksw = (l31 & 7) << 4;
  const int vsw = (l31 & 3) << 4;
  const int krow = tid >> 3;
  const int kce = ((16 * (tid & 7)) ^ ((krow & 7) << 4)) >> 1;
  const int vrow = tid >> 2;
  const int vce = ((16 * (tid & 3)) ^ ((vrow & 3) << 4)) >> 1;

#define STAGE(KT, BUF)                                                         \
  {                                                                            \
    const int jj = (KT) * 32;                                                  \
    bf16_t* base_ = (bf16_t*)(lds + (BUF) * 8192);                             \
    gld_lds16(Kh + (size_t)(jj + krow) * DH + kce, base_ + tid * 8);           \
    gld_lds16(Vh + (size_t)vrow * T_SEQ + jj + vce, base_ + 2048 + tid * 8);   \
  }

  STAGE(0, 0);
  __syncthreads();

  for (int kt = 0; kt <= KT_MAX; ++kt) {
    const int buf = kt & 1;
    if (kt < KT_MAX) STAGE(kt + 1, buf ^ 1);

    const bool doL = (kt <= tL);
    if (doL) {
      const char* kb = lds + buf * 8192;
      const char* vb = kb + 4096;
      bf16x8 kf[4];
#pragma unroll
      for (int dc = 0; dc < 4; dc++)
        kf[dc] = *(const bf16x8*)(kb + l31 * 128 + ((dc * 32 + hi * 16) ^ ksw));
      const bf16x8 vf00 = *(const bf16x8*)(vb + l31 * 64 + ((hi * 16) ^ vsw));
      const bf16x8 vf01 = *(const bf16x8*)(vb + l31 * 64 + ((32 + hi * 16) ^ vsw));
      const bf16x8 vf10 = *(const bf16x8*)(vb + (32 + l31) * 64 + ((hi * 16) ^ vsw));
      const bf16x8 vf11 = *(const bf16x8*)(vb + (32 + l31) * 64 + ((32 + hi * 16) ^ vsw));

      const bool doS = (kt <= tS);
      f32x16 sL = __builtin_amdgcn_mfma_f32_32x32x16_bf16(kf[0], qfL[0], z16, 0, 0, 0);
#pragma unroll
      for (int dc = 1; dc < 4; dc++)
        sL = __builtin_amdgcn_mfma_f32_32x32x16_bf16(kf[dc], qfL[dc], sL, 0, 0, 0);
      f32x16 sS;
      if (doS) {
        sS = __builtin_amdgcn_mfma_f32_32x32x16_bf16(kf[0], qfS[0], z16, 0, 0, 0);
#pragma unroll
        for (int dc = 1; dc < 4; dc++)
          sS = __builtin_amdgcn_mfma_f32_32x32x16_bf16(kf[dc], qfS[dc], sS, 0, 0, 0);
      }
      if (kt == tL) {
#pragma unroll
        for (int r = 0; r < 16; r++) {
          const int jrow = (r & 3) + 8 * (r >> 2) + 4 * hi;
          if (jrow > l31) sL[r] = -1e30f;
        }
      }
      if (kt == tS) {
#pragma unroll
        for (int r = 0; r < 16; r++) {
          const int jrow = (r & 3) + 8 * (r >> 2) + 4 * hi;
          if (jrow > l31) sS[r] = -1e30f;
        }
      }
      bf16x8 paL0, paL1;
      sm_pack(sL, mL, lL, oL0, oL1, paL0, paL1);
      oL0 = __builtin_amdgcn_mfma_f32_32x32x16_bf16(vf00, paL0, oL0, 0, 0, 0);
      oL1 = __builtin_amdgcn_mfma_f32_32x32x16_bf16(vf10, paL0, oL1, 0, 0, 0);
      oL0 = __builtin_amdgcn_mfma_f32_32x32x16_bf16(vf01, paL1, oL0, 0, 0, 0);
      oL1 = __builtin_amdgcn_mfma_f32_32x32x16_bf16(vf11, paL1, oL1, 0, 0, 0);
      if (doS) {
        bf16x8 paS0, paS1;
        sm_pack(sS, mS, lS, oS0, oS1, paS0, paS1);
        oS0 = __builtin_amdgcn_mfma_f32_32x32x16_bf16(vf00, paS0, oS0, 0, 0, 0);
        oS1 = __builtin_amdgcn_mfma_f32_32x32x16_bf16(vf10, paS0, oS1, 0, 0, 0);
        oS0 = __builtin_amdgcn_mfma_f32_32x32x16_bf16(vf01, paS1, oS0, 0, 0, 0);
        oS1 = __builtin_amdgcn_mfma_f32_32x32x16_bf16(vf11, paS1, oS1, 0, 0, 0);
      }
    }
    __syncthreads();
  }
#undef STAGE

  const int b = bh >> 4, h = bh & 15;
  store_o(oL0, oL1, lL, O + ((size_t)b * T_SEQ + q0L + l31) * C_DIM + h * DH, hi);
  store_o(oS0, oS1, lS, O + ((size_t)b * T_SEQ + q0S + l31) * C_DIM + h * DH, hi);
}

// ---------------------------------------------------------------------------
// launch
// ---------------------------------------------------------------------------
extern "C" void kernel_launch(void* const* d_in, const int* in_sizes, int n_in,
                              void* d_out, int out_size, void* d_ws, size_t ws_size,
                              hipStream_t stream) {
  const float* x  = (const float*)d_in[0];
  const float* wq = (const float*)d_in[2];
  const float* bq = (const float*)d_in[3];
  const float* wk = (const float*)d_in[4];
  const float* bk = (const float*)d_in[5];
  const float* wv = (const float*)d_in[6];
  const float* bv = (const float*)d_in[7];
  const float* wo = (const float*)d_in[8];
  const float* bo = (const float*)d_in[9];

  char* ws = (char*)d_ws;
  bf16_t* xb     = (bf16_t*)(ws);
  bf16_t* wt_qkv = (bf16_t*)(ws + (16ull << 20));
  bf16_t* wt_o   = (bf16_t*)(ws + (22ull << 20));
  bf16_t* qb     = (bf16_t*)(ws + (24ull << 20));
  bf16_t* kb     = (bf16_t*)(ws + (40ull << 20));
  bf16_t* vtb    = (bf16_t*)(ws + (56ull << 20));
  bf16_t* attn_o = xb;  // alias: xb dead after QKV GEMM

  const int n4 = M_TOK * C_DIM / 4;
  msa_cvt_x<<<n4 / 256, 256, 0, stream>>>(x, xb, n4);
  msa_transpose_w<<<dim3(32, 32, 4), 256, 0, stream>>>(wq, wk, wv, wo, wt_qkv, wt_o);
  msa_gemm_qkv<<<dim3(24, 64), 256, 0, stream>>>(xb, wt_qkv, bq, bk, bv, qb, kb, vtb);
  msa_attn_lds<<<dim3(64, 8), 256, 0, stream>>>(qb, kb, vtb, attn_o);
  msa_gemm_out<<<dim3(8, 64), 256, 0, stream>>>(attn_o, wt_o, bo, (float*)d_out);
}